// Round 12
// baseline (808.664 us; speedup 1.0000x reference)
//
#include <hip/hip_runtime.h>
#include <hip/hip_bf16.h>
#include <cstdint>
#include <cstddef>

#define B_  8
#define S_  1024
#define D_  1024
#define H_  8
#define FF_ 4096
#define L_  2
#define DK_ 128

typedef __bf16 bf16x8 __attribute__((ext_vector_type(8)));
typedef float  f32x4  __attribute__((ext_vector_type(4)));

__device__ __forceinline__ unsigned short f2bf(float f) {
    union { float f; uint32_t u; } v; v.f = f;
    uint32_t r = v.u + 0x7fffu + ((v.u >> 16) & 1u);
    return (unsigned short)(r >> 16);
}
__device__ __forceinline__ float bf2f(unsigned short u) {
    union { uint32_t u; float f; } v; v.u = ((uint32_t)u) << 16; return v.f;
}

// ---------------------------------------------------------------- init: xb = qe+pe, yb = qa+pe (bf16)
__global__ __launch_bounds__(256) void init_xy(
    const float* __restrict__ qe, const float* __restrict__ qa,
    const float* __restrict__ pe,
    unsigned short* __restrict__ xb, unsigned short* __restrict__ yb)
{
    int i = (blockIdx.x * 256 + threadIdx.x) * 4;
    int pi = i & (S_ * D_ - 1);
    float4 q = *(const float4*)(qe + i);
    float4 a = *(const float4*)(qa + i);
    float4 p = *(const float4*)(pe + pi);
    ushort4 xo; xo.x = f2bf(q.x + p.x); xo.y = f2bf(q.y + p.y);
    xo.z = f2bf(q.z + p.z); xo.w = f2bf(q.w + p.w);
    ushort4 yo; yo.x = f2bf(a.x + p.x); yo.y = f2bf(a.y + p.y);
    yo.z = f2bf(a.z + p.z); yo.w = f2bf(a.w + p.w);
    *(ushort4*)(xb + i) = xo;
    *(ushort4*)(yb + i) = yo;
}

// ---------------------------------------------------------------- fp32 -> bf16 weight convert (single tensor)
__global__ __launch_bounds__(256) void cvt_bf16(
    const float* __restrict__ in, unsigned short* __restrict__ out)
{
    int i = (blockIdx.x * 256 + threadIdx.x) * 4;
    float4 f = *(const float4*)(in + i);
    ushort4 o; o.x = f2bf(f.x); o.y = f2bf(f.y); o.z = f2bf(f.z); o.w = f2bf(f.w);
    *(ushort4*)(out + i) = o;
}

// ---------------------------------------------------------------- fp32 -> bf16, all 5 weight tensors, 1 launch
__global__ __launch_bounds__(256) void cvt_all(
    const float* __restrict__ wk, const float* __restrict__ wv,
    const float* __restrict__ wo, const float* __restrict__ w1,
    const float* __restrict__ w2, unsigned short* __restrict__ out)
{
    const size_t E0 = (size_t)L_ * D_ * D_;      // Wk
    const size_t E1 = 2 * E0;                    // +Wv
    const size_t E2 = 3 * E0;                    // +Wo
    const size_t E3 = E2 + (size_t)L_ * FF_ * D_;// +W1
    size_t i = ((size_t)blockIdx.x * 256 + threadIdx.x) * 4;
    const float* src;
    size_t off;
    if      (i < E0) { src = wk; off = i; }
    else if (i < E1) { src = wv; off = i - E0; }
    else if (i < E2) { src = wo; off = i - E1; }
    else if (i < E3) { src = w1; off = i - E2; }
    else             { src = w2; off = i - E3; }
    float4 f = *(const float4*)(src + off);
    ushort4 o; o.x = f2bf(f.x); o.y = f2bf(f.y); o.z = f2bf(f.z); o.w = f2bf(f.w);
    *(ushort4*)(out + i) = o;
}

// ---------------------------------------------------------------- dbuf m97-style bf16 MFMA NT-GEMM
// 128x128 tile, 4 waves. Proven ~820 TF on the N=1024 shapes.
// OMODE: 1 = bf16 row-major out; 2 = bf16 per-head-transposed [b,h][dim][key]
template<bool RELU, int OMODE>
__global__ __launch_bounds__(256) void gemm_bt(
    const unsigned short* __restrict__ A, const unsigned short* __restrict__ W,
    const float* __restrict__ bias, void* __restrict__ Cout,
    int M, int N, int K)
{
    __shared__ unsigned short sA[2][128][64];   // 2 x 16 KB
    __shared__ unsigned short sW[2][128][64];   // 2 x 16 KB

    const int tid  = threadIdx.x;
    const int lane = tid & 63;
    const int w    = tid >> 6;
    const int l16  = lane & 15;
    const int quad = lane >> 4;
    const int m0 = blockIdx.y * 128;
    const int n0 = blockIdx.x * 128;
    const int rw = (w >> 1) * 64;
    const int cw = (w & 1) * 64;

    const int srow   = lane >> 3;
    const int schunk = lane & 7;

    auto stage = [&](int k0, int buf) {
        #pragma unroll
        for (int i = 0; i < 4; ++i) {
            int r0  = w * 32 + i * 8;
            int row = r0 + srow;
            int gc  = schunk ^ (row & 7);
            const unsigned short* ga = A + (size_t)(m0 + row) * K + k0 + gc * 8;
            const unsigned short* gw = W + (size_t)(n0 + row) * K + k0 + gc * 8;
            __builtin_amdgcn_global_load_lds(
                (const __attribute__((address_space(1))) unsigned int*)ga,
                (__attribute__((address_space(3))) unsigned int*)&sA[buf][r0][0], 16, 0, 0);
            __builtin_amdgcn_global_load_lds(
                (const __attribute__((address_space(1))) unsigned int*)gw,
                (__attribute__((address_space(3))) unsigned int*)&sW[buf][r0][0], 16, 0, 0);
        }
    };

    f32x4 acc[4][4] = {};
    const int NK = K >> 6;
    int cur = 0;
    stage(0, 0);

    for (int kt = 0; kt < NK; ++kt) {
        __syncthreads();
        if (kt + 1 < NK) stage((kt + 1) << 6, cur ^ 1);

        #pragma unroll
        for (int ks = 0; ks < 2; ++ks) {
            bf16x8 af[4], wf[4];
            #pragma unroll
            for (int t = 0; t < 4; ++t) {
                int arow = rw + t * 16 + l16;
                int achk = (ks * 4 + quad) ^ (arow & 7);
                af[t] = *(const bf16x8*)&sA[cur][arow][achk * 8];
                int wrow = cw + t * 16 + l16;
                int wchk = (ks * 4 + quad) ^ (wrow & 7);
                wf[t] = *(const bf16x8*)&sW[cur][wrow][wchk * 8];
            }
            #pragma unroll
            for (int it = 0; it < 4; ++it)
                #pragma unroll
                for (int jt = 0; jt < 4; ++jt)
                    acc[it][jt] = __builtin_amdgcn_mfma_f32_16x16x32_bf16(
                        af[it], wf[jt], acc[it][jt], 0, 0, 0);
        }
        cur ^= 1;
    }

    #pragma unroll
    for (int it = 0; it < 4; ++it)
        #pragma unroll
        for (int jt = 0; jt < 4; ++jt) {
            int row = m0 + rw + it * 16 + quad * 4;
            int col = n0 + cw + jt * 16 + l16;
            float bcol = bias[col];
            float v[4];
            #pragma unroll
            for (int r = 0; r < 4; ++r) {
                v[r] = acc[it][jt][r] + bcol;
                if (RELU) v[r] = fmaxf(v[r], 0.0f);
            }
            if (OMODE == 1) {
                #pragma unroll
                for (int r = 0; r < 4; ++r)
                    ((unsigned short*)Cout)[(size_t)(row + r) * N + col] = f2bf(v[r]);
            } else {
                int key = row & (S_ - 1);
                int bb  = row >> 10;
                int hh  = col >> 7, dim = col & (DK_ - 1);
                unsigned short* dst = (unsigned short*)Cout
                    + ((size_t)(bb * H_ + hh) * DK_ + dim) * S_ + key;
                ushort4 o4; o4.x = f2bf(v[0]); o4.y = f2bf(v[1]);
                o4.z = f2bf(v[2]); o4.w = f2bf(v[3]);
                *(ushort4*)dst = o4;
            }
        }
}

// ---------------------------------------------------------------- fused K+V projection (one launch)
// blockIdx.z = 0: Kb = xb*Wk^T + bk (row-major); z = 1: Vt = yb*Wv^T + bv
// (per-head-transposed). Same proven gemm_bt loop; branch is block-uniform.
__global__ __launch_bounds__(256) void gemm_kv(
    const unsigned short* __restrict__ Ax, const unsigned short* __restrict__ Ay,
    const unsigned short* __restrict__ Wk, const unsigned short* __restrict__ Wv,
    const float* __restrict__ bk, const float* __restrict__ bv,
    unsigned short* __restrict__ Kb, unsigned short* __restrict__ Vt,
    int M, int N, int K)
{
    __shared__ unsigned short sA[2][128][64];
    __shared__ unsigned short sW[2][128][64];

    const int z = blockIdx.z;
    const unsigned short* A = z ? Ay : Ax;
    const unsigned short* W = z ? Wv : Wk;
    const float* bias = z ? bv : bk;

    const int tid  = threadIdx.x;
    const int lane = tid & 63;
    const int w    = tid >> 6;
    const int l16  = lane & 15;
    const int quad = lane >> 4;
    const int m0 = blockIdx.y * 128;
    const int n0 = blockIdx.x * 128;
    const int rw = (w >> 1) * 64;
    const int cw = (w & 1) * 64;

    const int srow   = lane >> 3;
    const int schunk = lane & 7;

    auto stage = [&](int k0, int buf) {
        #pragma unroll
        for (int i = 0; i < 4; ++i) {
            int r0  = w * 32 + i * 8;
            int row = r0 + srow;
            int gc  = schunk ^ (row & 7);
            const unsigned short* ga = A + (size_t)(m0 + row) * K + k0 + gc * 8;
            const unsigned short* gw = W + (size_t)(n0 + row) * K + k0 + gc * 8;
            __builtin_amdgcn_global_load_lds(
                (const __attribute__((address_space(1))) unsigned int*)ga,
                (__attribute__((address_space(3))) unsigned int*)&sA[buf][r0][0], 16, 0, 0);
            __builtin_amdgcn_global_load_lds(
                (const __attribute__((address_space(1))) unsigned int*)gw,
                (__attribute__((address_space(3))) unsigned int*)&sW[buf][r0][0], 16, 0, 0);
        }
    };

    f32x4 acc[4][4] = {};
    const int NK = K >> 6;
    int cur = 0;
    stage(0, 0);

    for (int kt = 0; kt < NK; ++kt) {
        __syncthreads();
        if (kt + 1 < NK) stage((kt + 1) << 6, cur ^ 1);

        #pragma unroll
        for (int ks = 0; ks < 2; ++ks) {
            bf16x8 af[4], wf[4];
            #pragma unroll
            for (int t = 0; t < 4; ++t) {
                int arow = rw + t * 16 + l16;
                int achk = (ks * 4 + quad) ^ (arow & 7);
                af[t] = *(const bf16x8*)&sA[cur][arow][achk * 8];
                int wrow = cw + t * 16 + l16;
                int wchk = (ks * 4 + quad) ^ (wrow & 7);
                wf[t] = *(const bf16x8*)&sW[cur][wrow][wchk * 8];
            }
            #pragma unroll
            for (int it = 0; it < 4; ++it)
                #pragma unroll
                for (int jt = 0; jt < 4; ++jt)
                    acc[it][jt] = __builtin_amdgcn_mfma_f32_16x16x32_bf16(
                        af[it], wf[jt], acc[it][jt], 0, 0, 0);
        }
        cur ^= 1;
    }

    #pragma unroll
    for (int it = 0; it < 4; ++it)
        #pragma unroll
        for (int jt = 0; jt < 4; ++jt) {
            int row = m0 + rw + it * 16 + quad * 4;
            int col = n0 + cw + jt * 16 + l16;
            float bcol = bias[col];
            float v[4];
            #pragma unroll
            for (int r = 0; r < 4; ++r) v[r] = acc[it][jt][r] + bcol;
            if (z == 0) {
                #pragma unroll
                for (int r = 0; r < 4; ++r)
                    Kb[(size_t)(row + r) * N + col] = f2bf(v[r]);
            } else {
                int key = row & (S_ - 1);
                int bb  = row >> 10;
                int hh  = col >> 7, dim = col & (DK_ - 1);
                unsigned short* dst = Vt
                    + ((size_t)(bb * H_ + hh) * DK_ + dim) * S_ + key;
                ushort4 o4; o4.x = f2bf(v[0]); o4.y = f2bf(v[1]);
                o4.z = f2bf(v[2]); o4.w = f2bf(v[3]);
                *(ushort4*)dst = o4;
            }
        }
}

// ---------------------------------------------------------------- 256x256 4-phase spread counted-vmcnt NT-GEMM
// m201-cadence: each phase = {ds-reads, stage issue, s_barrier, setprio(1),
// 16 MFMA, setprio(0), [wait+]s_barrier}. Leading barrier creates the clean
// phase-split (early-finishing waves issue next-phase loads while laggards
// MFMA under raised prio -- the T5 role-split, m218b). Counted vmcnt ledger
// unchanged: mid-tile vmcnt(6) drains this tile's A1,A3; boundary vmcnt(2).
template<bool RELU>
__global__ __launch_bounds__(512, 2) void gemm_bt8(
    const unsigned short* __restrict__ A, const unsigned short* __restrict__ W,
    const float* __restrict__ bias, unsigned short* __restrict__ Cout,
    int M, int N, int K)
{
    __shared__ unsigned short sA[2][256][64];   // 2 x 32 KB
    __shared__ unsigned short sB[2][256][64];   // 2 x 32 KB

    const int tid  = threadIdx.x;
    const int lane = tid & 63;
    const int w    = tid >> 6;
    const int l16  = lane & 15;
    const int quad = lane >> 4;
    const int wr   = w >> 2;
    const int wc   = w & 3;

    const int nwg = gridDim.x * gridDim.y;
    const int bid = blockIdx.y * gridDim.x + blockIdx.x;
    const int sb  = (bid & 7) * (nwg >> 3) + (bid >> 3);
    const int m0  = (sb / gridDim.x) * 256;
    const int n0  = (sb % gridDim.x) * 256;

    const int srow8 = lane >> 3;
    const int schk  = (lane & 7) ^ srow8;

    auto stA = [&](int i, int buf, int k0) {
        int r0 = i * 64 + w * 8;
        const unsigned short* g = A + (size_t)(m0 + r0 + srow8) * K + k0 + schk * 8;
        __builtin_amdgcn_global_load_lds(
            (const __attribute__((address_space(1))) unsigned int*)g,
            (__attribute__((address_space(3))) unsigned int*)&sA[buf][r0][0], 16, 0, 0);
    };
    auto stB = [&](int i, int buf, int k0) {
        int r0 = i * 64 + w * 8;
        const unsigned short* g = W + (size_t)(n0 + r0 + srow8) * K + k0 + schk * 8;
        __builtin_amdgcn_global_load_lds(
            (const __attribute__((address_space(1))) unsigned int*)g,
            (__attribute__((address_space(3))) unsigned int*)&sB[buf][r0][0], 16, 0, 0);
    };
    auto rdA = [&](int buf, int t, int ks) {
        int row = wr * 128 + t * 16 + l16;
        int chk = (ks * 4 + quad) ^ (row & 7);
        return *(const bf16x8*)&sA[buf][row][chk * 8];
    };
    auto rdB = [&](int buf, int j, int ks) {
        int row = wc * 64 + j * 16 + l16;
        int chk = (ks * 4 + quad) ^ (row & 7);
        return *(const bf16x8*)&sB[buf][row][chk * 8];
    };

    f32x4 acc[8][4] = {};
    const int NK = K >> 6;
    int cur = 0;

    stB(0, 0, 0); stB(1, 0, 0); stB(2, 0, 0); stB(3, 0, 0);
    stA(0, 0, 0); stA(2, 0, 0); stA(1, 0, 0); stA(3, 0, 0);
    asm volatile("s_waitcnt vmcnt(2)\n\ts_barrier" ::: "memory");

    for (int kt = 0; kt < NK; ++kt) {
        const bool pref = (kt + 1 < NK);
        const int  k1   = (kt + 1) << 6;
        const int  nb   = cur ^ 1;
        bf16x8 bfr[2][4];
        bf16x8 a0, a1, a2, a3;

        // ---- phase 0: row-tiles 0,1 (A bands 0/2)
        #pragma unroll
        for (int ks = 0; ks < 2; ++ks)
            #pragma unroll
            for (int j = 0; j < 4; ++j) bfr[ks][j] = rdB(cur, j, ks);
        a0 = rdA(cur, 0, 0); a1 = rdA(cur, 0, 1);
        a2 = rdA(cur, 1, 0); a3 = rdA(cur, 1, 1);
        if (pref) { stB(0, nb, k1); stB(1, nb, k1); stB(2, nb, k1); }
        asm volatile("s_barrier" ::: "memory");
        __builtin_amdgcn_s_setprio(1);
        #pragma unroll
        for (int j = 0; j < 4; ++j) {
            acc[0][j] = __builtin_amdgcn_mfma_f32_16x16x32_bf16(a0, bfr[0][j], acc[0][j], 0, 0, 0);
            acc[1][j] = __builtin_amdgcn_mfma_f32_16x16x32_bf16(a2, bfr[0][j], acc[1][j], 0, 0, 0);
        }
        #pragma unroll
        for (int j = 0; j < 4; ++j) {
            acc[0][j] = __builtin_amdgcn_mfma_f32_16x16x32_bf16(a1, bfr[1][j], acc[0][j], 0, 0, 0);
            acc[1][j] = __builtin_amdgcn_mfma_f32_16x16x32_bf16(a3, bfr[1][j], acc[1][j], 0, 0, 0);
        }
        __builtin_amdgcn_s_setprio(0);
        asm volatile("s_barrier" ::: "memory");

        // ---- phase 1: row-tiles 2,3 (still A bands 0/2)
        a0 = rdA(cur, 2, 0); a1 = rdA(cur, 2, 1);
        a2 = rdA(cur, 3, 0); a3 = rdA(cur, 3, 1);
        if (pref) { stB(3, nb, k1); stA(0, nb, k1); stA(2, nb, k1); }
        asm volatile("s_barrier" ::: "memory");
        __builtin_amdgcn_s_setprio(1);
        #pragma unroll
        for (int j = 0; j < 4; ++j) {
            acc[2][j] = __builtin_amdgcn_mfma_f32_16x16x32_bf16(a0, bfr[0][j], acc[2][j], 0, 0, 0);
            acc[3][j] = __builtin_amdgcn_mfma_f32_16x16x32_bf16(a2, bfr[0][j], acc[3][j], 0, 0, 0);
        }
        #pragma unroll
        for (int j = 0; j < 4; ++j) {
            acc[2][j] = __builtin_amdgcn_mfma_f32_16x16x32_bf16(a1, bfr[1][j], acc[2][j], 0, 0, 0);
            acc[3][j] = __builtin_amdgcn_mfma_f32_16x16x32_bf16(a3, bfr[1][j], acc[3][j], 0, 0, 0);
        }
        __builtin_amdgcn_s_setprio(0);
        // mid-tile: drain THIS tile's A1,A3 (oldest 2); next tile's 6 ride
        if (pref) asm volatile("s_waitcnt vmcnt(6)\n\ts_barrier" ::: "memory");
        else      asm volatile("s_waitcnt vmcnt(0)\n\ts_barrier" ::: "memory");

        // ---- phase 2: row-tiles 4,5 (A bands 1/3 now resident)
        a0 = rdA(cur, 4, 0); a1 = rdA(cur, 4, 1);
        a2 = rdA(cur, 5, 0); a3 = rdA(cur, 5, 1);
        if (pref) { stA(1, nb, k1); stA(3, nb, k1); }
        asm volatile("s_barrier" ::: "memory");
        __builtin_amdgcn_s_setprio(1);
        #pragma unroll
        for (int j = 0; j < 4; ++j) {
            acc[4][j] = __builtin_amdgcn_mfma_f32_16x16x32_bf16(a0, bfr[0][j], acc[4][j], 0, 0, 0);
            acc[5][j] = __builtin_amdgcn_mfma_f32_16x16x32_bf16(a2, bfr[0][j], acc[5][j], 0, 0, 0);
        }
        #pragma unroll
        for (int j = 0; j < 4; ++j) {
            acc[4][j] = __builtin_amdgcn_mfma_f32_16x16x32_bf16(a1, bfr[1][j], acc[4][j], 0, 0, 0);
            acc[5][j] = __builtin_amdgcn_mfma_f32_16x16x32_bf16(a3, bfr[1][j], acc[5][j], 0, 0, 0);
        }
        __builtin_amdgcn_s_setprio(0);
        asm volatile("s_barrier" ::: "memory");

        // ---- phase 3: row-tiles 6,7
        a0 = rdA(cur, 6, 0); a1 = rdA(cur, 6, 1);
        a2 = rdA(cur, 7, 0); a3 = rdA(cur, 7, 1);
        asm volatile("s_barrier" ::: "memory");
        __builtin_amdgcn_s_setprio(1);
        #pragma unroll
        for (int j = 0; j < 4; ++j) {
            acc[6][j] = __builtin_amdgcn_mfma_f32_16x16x32_bf16(a0, bfr[0][j], acc[6][j], 0, 0, 0);
            acc[7][j] = __builtin_amdgcn_mfma_f32_16x16x32_bf16(a2, bfr[0][j], acc[7][j], 0, 0, 0);
        }
        #pragma unroll
        for (int j = 0; j < 4; ++j) {
            acc[6][j] = __builtin_amdgcn_mfma_f32_16x16x32_bf16(a1, bfr[1][j], acc[6][j], 0, 0, 0);
            acc[7][j] = __builtin_amdgcn_mfma_f32_16x16x32_bf16(a3, bfr[1][j], acc[7][j], 0, 0, 0);
        }
        __builtin_amdgcn_s_setprio(0);
        // boundary: next tile's phase-0 set resident; its A1,A3 ride across
        asm volatile("s_waitcnt vmcnt(2)\n\ts_barrier" ::: "memory");
        cur = nb;
    }

    #pragma unroll
    for (int t = 0; t < 8; ++t)
        #pragma unroll
        for (int j = 0; j < 4; ++j) {
            int row = m0 + wr * 128 + t * 16 + quad * 4;
            int col = n0 + wc * 64 + j * 16 + l16;
            float bcol = bias[col];
            #pragma unroll
            for (int r = 0; r < 4; ++r) {
                float v = acc[t][j][r] + bcol;
                if (RELU) v = fmaxf(v, 0.0f);
                Cout[(size_t)(row + r) * N + col] = f2bf(v);
            }
        }
}

// ---------------------------------------------------------------- split-K gemm_bt8: fp32 partials, no bias
// Same m201-cadence loop; blockIdx.z picks the K-half. Combine fused in ln_res_sk.
__global__ __launch_bounds__(512, 2) void gemm_sk(
    const unsigned short* __restrict__ A, const unsigned short* __restrict__ W,
    float* __restrict__ P, int M, int N, int K, int Kh)
{
    __shared__ unsigned short sA[2][256][64];
    __shared__ unsigned short sB[2][256][64];

    const int tid  = threadIdx.x;
    const int lane = tid & 63;
    const int w    = tid >> 6;
    const int l16  = lane & 15;
    const int quad = lane >> 4;
    const int wr   = w >> 2;
    const int wc   = w & 3;

    const int nwg = gridDim.x * gridDim.y;
    const int bid = blockIdx.y * gridDim.x + blockIdx.x;
    const int sb  = (bid & 7) * (nwg >> 3) + (bid >> 3);
    const int m0  = (sb / gridDim.x) * 256;
    const int n0  = (sb % gridDim.x) * 256;
    const int kb  = blockIdx.z * Kh;
    P += (size_t)blockIdx.z * M * N;

    const int srow8 = lane >> 3;
    const int schk  = (lane & 7) ^ srow8;

    auto stA = [&](int i, int buf, int k0) {
        int r0 = i * 64 + w * 8;
        const unsigned short* g = A + (size_t)(m0 + r0 + srow8) * K + k0 + schk * 8;
        __builtin_amdgcn_global_load_lds(
            (const __attribute__((address_space(1))) unsigned int*)g,
            (__attribute__((address_space(3))) unsigned int*)&sA[buf][r0][0], 16, 0, 0);
    };
    auto stB = [&](int i, int buf, int k0) {
        int r0 = i * 64 + w * 8;
        const unsigned short* g = W + (size_t)(n0 + r0 + srow8) * K + k0 + schk * 8;
        __builtin_amdgcn_global_load_lds(
            (const __attribute__((address_space(1))) unsigned int*)g,
            (__attribute__((address_space(3))) unsigned int*)&sB[buf][r0][0], 16, 0, 0);
    };
    auto rdA = [&](int buf, int t, int ks) {
        int row = wr * 128 + t * 16 + l16;
        int chk = (ks * 4 + quad) ^ (row & 7);
        return *(const bf16x8*)&sA[buf][row][chk * 8];
    };
    auto rdB = [&](int buf, int j, int ks) {
        int row = wc * 64 + j * 16 + l16;
        int chk = (ks * 4 + quad) ^ (row & 7);
        return *(const bf16x8*)&sB[buf][row][chk * 8];
    };

    f32x4 acc[8][4] = {};
    const int NK = Kh >> 6;
    int cur = 0;

    stB(0, 0, kb); stB(1, 0, kb); stB(2, 0, kb); stB(3, 0, kb);
    stA(0, 0, kb); stA(2, 0, kb); stA(1, 0, kb); stA(3, 0, kb);
    asm volatile("s_waitcnt vmcnt(2)\n\ts_barrier" ::: "memory");

    for (int kt = 0; kt < NK; ++kt) {
        const bool pref = (kt + 1 < NK);
        const int  k1   = kb + ((kt + 1) << 6);
        const int  nb   = cur ^ 1;
        bf16x8 bfr[2][4];
        bf16x8 a0, a1, a2, a3;

        // ---- phase 0
        #pragma unroll
        for (int ks = 0; ks < 2; ++ks)
            #pragma unroll
            for (int j = 0; j < 4; ++j) bfr[ks][j] = rdB(cur, j, ks);
        a0 = rdA(cur, 0, 0); a1 = rdA(cur, 0, 1);
        a2 = rdA(cur, 1, 0); a3 = rdA(cur, 1, 1);
        if (pref) { stB(0, nb, k1); stB(1, nb, k1); stB(2, nb, k1); }
        asm volatile("s_barrier" ::: "memory");
        __builtin_amdgcn_s_setprio(1);
        #pragma unroll
        for (int j = 0; j < 4; ++j) {
            acc[0][j] = __builtin_amdgcn_mfma_f32_16x16x32_bf16(a0, bfr[0][j], acc[0][j], 0, 0, 0);
            acc[1][j] = __builtin_amdgcn_mfma_f32_16x16x32_bf16(a2, bfr[0][j], acc[1][j], 0, 0, 0);
        }
        #pragma unroll
        for (int j = 0; j < 4; ++j) {
            acc[0][j] = __builtin_amdgcn_mfma_f32_16x16x32_bf16(a1, bfr[1][j], acc[0][j], 0, 0, 0);
            acc[1][j] = __builtin_amdgcn_mfma_f32_16x16x32_bf16(a3, bfr[1][j], acc[1][j], 0, 0, 0);
        }
        __builtin_amdgcn_s_setprio(0);
        asm volatile("s_barrier" ::: "memory");

        // ---- phase 1
        a0 = rdA(cur, 2, 0); a1 = rdA(cur, 2, 1);
        a2 = rdA(cur, 3, 0); a3 = rdA(cur, 3, 1);
        if (pref) { stB(3, nb, k1); stA(0, nb, k1); stA(2, nb, k1); }
        asm volatile("s_barrier" ::: "memory");
        __builtin_amdgcn_s_setprio(1);
        #pragma unroll
        for (int j = 0; j < 4; ++j) {
            acc[2][j] = __builtin_amdgcn_mfma_f32_16x16x32_bf16(a0, bfr[0][j], acc[2][j], 0, 0, 0);
            acc[3][j] = __builtin_amdgcn_mfma_f32_16x16x32_bf16(a2, bfr[0][j], acc[3][j], 0, 0, 0);
        }
        #pragma unroll
        for (int j = 0; j < 4; ++j) {
            acc[2][j] = __builtin_amdgcn_mfma_f32_16x16x32_bf16(a1, bfr[1][j], acc[2][j], 0, 0, 0);
            acc[3][j] = __builtin_amdgcn_mfma_f32_16x16x32_bf16(a3, bfr[1][j], acc[3][j], 0, 0, 0);
        }
        __builtin_amdgcn_s_setprio(0);
        if (pref) asm volatile("s_waitcnt vmcnt(6)\n\ts_barrier" ::: "memory");
        else      asm volatile("s_waitcnt vmcnt(0)\n\ts_barrier" ::: "memory");

        // ---- phase 2
        a0 = rdA(cur, 4, 0); a1 = rdA(cur, 4, 1);
        a2 = rdA(cur, 5, 0); a3 = rdA(cur, 5, 1);
        if (pref) { stA(1, nb, k1); stA(3, nb, k1); }
        asm volatile("s_barrier" ::: "memory");
        __builtin_amdgcn_s_setprio(1);
        #pragma unroll
        for (int j = 0; j < 4; ++j) {
            acc[4][j] = __builtin_amdgcn_mfma_f32_16x16x32_bf16(a0, bfr[0][j], acc[4][j], 0, 0, 0);
            acc[5][j] = __builtin_amdgcn_mfma_f32_16x16x32_bf16(a2, bfr[0][j], acc[5][j], 0, 0, 0);
        }
        #pragma unroll
        for (int j = 0; j < 4; ++j) {
            acc[4][j] = __builtin_amdgcn_mfma_f32_16x16x32_bf16(a1, bfr[1][j], acc[4][j], 0, 0, 0);
            acc[5][j] = __builtin_amdgcn_mfma_f32_16x16x32_bf16(a3, bfr[1][j], acc[5][j], 0, 0, 0);
        }
        __builtin_amdgcn_s_setprio(0);
        asm volatile("s_barrier" ::: "memory");

        // ---- phase 3
        a0 = rdA(cur, 6, 0); a1 = rdA(cur, 6, 1);
        a2 = rdA(cur, 7, 0); a3 = rdA(cur, 7, 1);
        asm volatile("s_barrier" ::: "memory");
        __builtin_amdgcn_s_setprio(1);
        #pragma unroll
        for (int j = 0; j < 4; ++j) {
            acc[6][j] = __builtin_amdgcn_mfma_f32_16x16x32_bf16(a0, bfr[0][j], acc[6][j], 0, 0, 0);
            acc[7][j] = __builtin_amdgcn_mfma_f32_16x16x32_bf16(a2, bfr[0][j], acc[7][j], 0, 0, 0);
        }
        #pragma unroll
        for (int j = 0; j < 4; ++j) {
            acc[6][j] = __builtin_amdgcn_mfma_f32_16x16x32_bf16(a1, bfr[1][j], acc[6][j], 0, 0, 0);
            acc[7][j] = __builtin_amdgcn_mfma_f32_16x16x32_bf16(a3, bfr[1][j], acc[7][j], 0, 0, 0);
        }
        __builtin_amdgcn_s_setprio(0);
        asm volatile("s_waitcnt vmcnt(2)\n\ts_barrier" ::: "memory");
        cur = nb;
    }

    #pragma unroll
    for (int t = 0; t < 8; ++t)
        #pragma unroll
        for (int j = 0; j < 4; ++j) {
            int row = m0 + wr * 128 + t * 16 + quad * 4;
            int col = n0 + wc * 64 + j * 16 + l16;
            #pragma unroll
            for (int r = 0; r < 4; ++r)
                P[(size_t)(row + r) * N + col] = acc[t][j][r];
        }
}

// ---------------------------------------------------------------- MFMA flash attention (proven form)
// Q == K (kq_same). Strict causal (j < q). Row 0 output = 0 (zero_pad).
// XCD-locality swizzle; defer-max (THR=8); K+V LDS dbuf via global_load_lds.
__global__ __launch_bounds__(256) void attn_mfma(
    const unsigned short* __restrict__ Kbuf, const unsigned short* __restrict__ Vtbuf,
    unsigned short* __restrict__ Obuf)
{
    __shared__ unsigned short sK[2][64][128];
    __shared__ unsigned short sVt[2][128][64];
    __shared__ unsigned short sP[4][16][72];

    const int tid  = threadIdx.x;
    const int lane = tid & 63;
    const int w    = tid >> 6;
    const int l16  = lane & 15;
    const int quad = lane >> 4;

    const int ib   = blockIdx.y * 8 + blockIdx.x;
    const int pa   = (ib >> 3) & 7;
    const int bh   = (ib & 7) + ((ib >> 6) << 3);
    const int b    = bh >> 3, h = bh & 7;
    const unsigned short* KB  = Kbuf  + ((size_t)b * S_) * D_ + h * DK_;
    const unsigned short* VTB = Vtbuf + (size_t)bh * DK_ * S_;

    const float scale = 0.08838834764831845f;

    auto stage = [&](int kt, int buf) {
        #pragma unroll
        for (int i = 0; i < 4; ++i) {
            int r0  = w * 16 + i * 4;
            int row = r0 + (lane >> 4);
            int c   = (lane & 15) ^ (row & 15);
            const unsigned short* g = KB + (size_t)(kt * 64 + row) * D_ + c * 8;
            __builtin_amdgcn_global_load_lds(
                (const __attribute__((address_space(1))) unsigned int*)g,
                (__attribute__((address_space(3))) unsigned int*)&sK[buf][r0][0], 16, 0, 0);
        }
        #pragma unroll
        for (int i = 0; i < 4; ++i) {
            int r0  = w * 32 + i * 8;
            int row = r0 + (lane >> 3);
            int c   = (lane & 7) ^ (row & 7);
            const unsigned short* g = VTB + (size_t)row * S_ + kt * 64 + c * 8;
            __builtin_amdgcn_global_load_lds(
                (const __attribute__((address_space(1))) unsigned int*)g,
                (__attribute__((address_space(3))) unsigned int*)&sVt[buf][r0][0], 16, 0, 0);
        }
    };

    #pragma unroll
    for (int half = 0; half < 2; ++half) {
        const int qt = half == 0 ? (15 - pa) : pa;
        const int q0 = qt * 64;

        bf16x8 qf[4];
        {
            const unsigned short* qrow = KB + (size_t)(q0 + w * 16 + l16) * D_ + quad * 8;
            #pragma unroll
            for (int ks = 0; ks < 4; ++ks)
                qf[ks] = *(const bf16x8*)(qrow + ks * 32);
        }

        f32x4 Oacc[8] = {};
        float m_run[4] = {-1e30f, -1e30f, -1e30f, -1e30f};
        float l_run[4] = {};

        int cur = 0;
        stage(0, cur);

        for (int kt = 0; kt <= qt; ++kt) {
            __syncthreads();
            if (kt < qt) stage(kt + 1, cur ^ 1);

            f32x4 sacc[4];
            __builtin_amdgcn_s_setprio(1);
            #pragma unroll
            for (int nt = 0; nt < 4; ++nt) {
                f32x4 a = {};
                #pragma unroll
                for (int ks = 0; ks < 4; ++ks) {
                    int kr = nt * 16 + l16;
                    int p  = (ks * 4 + quad) ^ (kr & 15);
                    bf16x8 kf = *(const bf16x8*)&sK[cur][kr][p * 8];
                    a = __builtin_amdgcn_mfma_f32_16x16x32_bf16(qf[ks], kf, a, 0, 0, 0);
                }
                sacc[nt] = a;
            }
            __builtin_amdgcn_s_setprio(0);

            const bool diag = (kt == qt);
            #pragma unroll
            for (int nt = 0; nt < 4; ++nt)
                #pragma unroll
                for (int r = 0; r < 4; ++r) {
                    float v = sacc[nt][r] * scale;
                    if (diag) {
                        int nidx = nt * 16 + l16;
                        int midx = w * 16 + quad * 4 + r;
                        if (nidx >= midx) v = -1e30f;
                    }
                    sacc[nt][r] = v;
                }

            float mx[4];
            #pragma unroll
            for (int r = 0; r < 4; ++r) {
                float m = fmaxf(fmaxf(sacc[0][r], sacc[1][r]), fmaxf(sacc[2][r], sacc[3][r]));
                m = fmaxf(m, __shfl_xor(m, 1));
                m = fmaxf(m, __shfl_xor(m, 2));
                m = fmaxf(m, __shfl_xor(m, 4));
                m = fmaxf(m, __shfl_xor(m, 8));
                mx[r] = m;
            }
            bool need = false;
            #pragma unroll
            for (int r = 0; r < 4; ++r) need |= (mx[r] > m_run[r] + 8.0f);
            if (__any(need)) {
                #pragma unroll
                for (int r = 0; r < 4; ++r) {
                    float mn = fmaxf(m_run[r], mx[r]);
                    float alpha = __expf(m_run[r] - mn);
                    m_run[r] = mn;
                    l_run[r] *= alpha;
                    #pragma unroll
                    for (int o = 0; o < 8; ++o) Oacc[o][r] *= alpha;
                }
            }
            #pragma unroll
            for (int r = 0; r < 4; ++r) {
                float rs = 0.0f;
                #pragma unroll
                for (int nt = 0; nt < 4; ++nt) {
                    float e = __expf(sacc[nt][r] - m_run[r]);
                    sacc[nt][r] = e;
                    rs += e;
                }
                rs += __shfl_xor(rs, 1);
                rs += __shfl_xor(rs, 2);
                rs += __shfl_xor(rs, 4);
                rs += __shfl_xor(rs, 8);
                l_run[r] += rs;
            }

            #pragma unroll
            for (int nt = 0; nt < 4; ++nt)
                #pragma unroll
                for (int r = 0; r < 4; ++r)
                    sP[w][quad * 4 + r][nt * 16 + l16] = f2bf(sacc[nt][r]);

            bf16x8 pf[2];
            #pragma unroll
            for (int ks = 0; ks < 2; ++ks)
                pf[ks] = *(const bf16x8*)&sP[w][l16][ks * 32 + quad * 8];
            __builtin_amdgcn_s_setprio(1);
            #pragma unroll
            for (int nt = 0; nt < 8; ++nt) {
                #pragma unroll
                for (int ks = 0; ks < 2; ++ks) {
                    int vr = nt * 16 + l16;
                    int p  = (ks * 4 + quad) ^ (vr & 7);
                    bf16x8 vf = *(const bf16x8*)&sVt[cur][vr][p * 8];
                    Oacc[nt] = __builtin_amdgcn_mfma_f32_16x16x32_bf16(pf[ks], vf, Oacc[nt], 0, 0, 0);
                }
            }
            __builtin_amdgcn_s_setprio(0);
            cur ^= 1;
        }

        float inv[4];
        #pragma unroll
        for (int r = 0; r < 4; ++r) {
            int m = q0 + w * 16 + quad * 4 + r;
            inv[r] = (l_run[r] > 0.0f && m != 0) ? 1.0f / l_run[r] : 0.0f;
        }
        #pragma unroll
        for (int nt = 0; nt < 8; ++nt)
            #pragma unroll
            for (int r = 0; r < 4; ++r) {
                int m = q0 + w * 16 + quad * 4 + r;
                Obuf[((size_t)b * S_ + m) * D_ + h * DK_ + nt * 16 + l16] =
                    f2bf(Oacc[nt][r] * inv[r]);
            }
    }
}

// ---------------------------------------------------------------- residual + LayerNorm (bf16 delta)
template<bool FINAL>
__global__ __launch_bounds__(256) void ln_res(
    const unsigned short* __restrict__ xin, const unsigned short* __restrict__ delta,
    const float* __restrict__ g, const float* __restrict__ bta,
    unsigned short* __restrict__ xbout, float* __restrict__ fout)
{
    __shared__ float red1[4], red2[4];
    const int row = blockIdx.x;
    const int tid = threadIdx.x;
    const int c = tid * 4;
    ushort4 xu = *(const ushort4*)(xin + (size_t)row * D_ + c);
    ushort4 du = *(const ushort4*)(delta + (size_t)row * D_ + c);
    float t0 = bf2f(xu.x) + bf2f(du.x), t1 = bf2f(xu.y) + bf2f(du.y);
    float t2 = bf2f(xu.z) + bf2f(du.z), t3 = bf2f(xu.w) + bf2f(du.w);

    float s = t0 + t1 + t2 + t3;
    #pragma unroll
    for (int off = 32; off > 0; off >>= 1) s += __shfl_down(s, off);
    if ((tid & 63) == 0) red1[tid >> 6] = s;
    __syncthreads();
    float mean = (red1[0] + red1[1] + red1[2] + red1[3]) * (1.0f / 1024.0f);

    float e0 = t0 - mean, e1 = t1 - mean, e2 = t2 - mean, e3 = t3 - mean;
    float ss = e0 * e0 + e1 * e1 + e2 * e2 + e3 * e3;
    #pragma unroll
    for (int off = 32; off > 0; off >>= 1) ss += __shfl_down(ss, off);
    if ((tid & 63) == 0) red2[tid >> 6] = ss;
    __syncthreads();
    float var = (red2[0] + red2[1] + red2[2] + red2[3]) * (1.0f / 1024.0f);
    float rstd = rsqrtf(var + 1e-5f);

    float4 gv = *(const float4*)(g + c);
    float4 bv = *(const float4*)(bta + c);
    float o0 = e0 * rstd * gv.x + bv.x;
    float o1 = e1 * rstd * gv.y + bv.y;
    float o2 = e2 * rstd * gv.z + bv.z;
    float o3 = e3 * rstd * gv.w + bv.w;
    if (FINAL) {
        *(float4*)(fout + (size_t)row * D_ + c) = make_float4(o0, o1, o2, o3);
    } else {
        ushort4 ob; ob.x = f2bf(o0); ob.y = f2bf(o1); ob.z = f2bf(o2); ob.w = f2bf(o3);
        *(ushort4*)(xbout + (size_t)row * D_ + c) = ob;
    }
}

// ---------------------------------------------------------------- residual + LN, split-K combine fused
template<bool FINAL>
__global__ __launch_bounds__(256) void ln_res_sk(
    const unsigned short* __restrict__ xin,
    const float* __restrict__ p0, const float* __restrict__ p1,
    const float* __restrict__ wbias,
    const float* __restrict__ g, const float* __restrict__ bta,
    unsigned short* __restrict__ xbout, float* __restrict__ fout)
{
    __shared__ float red1[4], red2[4];
    const int row = blockIdx.x;
    const int tid = threadIdx.x;
    const int c = tid * 4;
    ushort4 xu = *(const ushort4*)(xin + (size_t)row * D_ + c);
    float4 a0 = *(const float4*)(p0 + (size_t)row * D_ + c);
    float4 a1 = *(const float4*)(p1 + (size_t)row * D_ + c);
    float4 wb = *(const float4*)(wbias + c);
    float t0 = bf2f(xu.x) + a0.x + a1.x + wb.x;
    float t1 = bf2f(xu.y) + a0.y + a1.y + wb.y;
    float t2 = bf2f(xu.z) + a0.z + a1.z + wb.z;
    float t3 = bf2f(xu.w) + a0.w + a1.w + wb.w;

    float s = t0 + t1 + t2 + t3;
    #pragma unroll
    for (int off = 32; off > 0; off >>= 1) s += __shfl_down(s, off);
    if ((tid & 63) == 0) red1[tid >> 6] = s;
    __syncthreads();
    float mean = (red1[0] + red1[1] + red1[2] + red1[3]) * (1.0f / 1024.0f);

    float e0 = t0 - mean, e1 = t1 - mean, e2 = t2 - mean, e3 = t3 - mean;
    float ss = e0 * e0 + e1 * e1 + e2 * e2 + e3 * e3;
    #pragma unroll
    for (int off = 32; off > 0; off >>= 1) ss += __shfl_down(ss, off);
    if ((tid & 63) == 0) red2[tid >> 6] = ss;
    __syncthreads();
    float var = (red2[0] + red2[1] + red2[2] + red2[3]) * (1.0f / 1024.0f);
    float rstd = rsqrtf(var + 1e-5f);

    float4 gv = *(const float4*)(g + c);
    float4 bv = *(const float4*)(bta + c);
    float o0 = e0 * rstd * gv.x + bv.x;
    float o1 = e1 * rstd * gv.y + bv.y;
    float o2 = e2 * rstd * gv.z + bv.z;
    float o3 = e3 * rstd * gv.w + bv.w;
    if (FINAL) {
        *(float4*)(fout + (size_t)row * D_ + c) = make_float4(o0, o1, o2, o3);
    } else {
        ushort4 ob; ob.x = f2bf(o0); ob.y = f2bf(o1); ob.z = f2bf(o2); ob.w = f2bf(o3);
        *(ushort4*)(xbout + (size_t)row * D_ + c) = ob;
    }
}

// ---------------------------------------------------------------- driver
extern "C" void kernel_launch(void* const* d_in, const int* in_sizes, int n_in,
                              void* d_out, int out_size, void* d_ws, size_t ws_size,
                              hipStream_t stream)
{
    const float* qe   = (const float*)d_in[0];
    const float* qa   = (const float*)d_in[1];
    const float* pe   = (const float*)d_in[2];
    const float* Wk   = (const float*)d_in[3];
    const float* bk   = (const float*)d_in[4];
    const float* Wv   = (const float*)d_in[5];
    const float* bv   = (const float*)d_in[6];
    const float* Wo   = (const float*)d_in[7];
    const float* bo   = (const float*)d_in[8];
    const float* ln1g = (const float*)d_in[9];
    const float* ln1b = (const float*)d_in[10];
    const float* W1   = (const float*)d_in[11];
    const float* b1   = (const float*)d_in[12];
    const float* W2   = (const float*)d_in[13];
    const float* b2   = (const float*)d_in[14];
    const float* ln2g = (const float*)d_in[15];
    const float* ln2b = (const float*)d_in[16];

    const size_t BSD = (size_t)B_ * S_ * D_;
    const size_t BSF = (size_t)B_ * S_ * FF_;
    const size_t WDD = (size_t)D_ * D_;
    const size_t WFD = (size_t)FF_ * D_;

    char* p = (char*)d_ws;
    auto take = [&](size_t bytes) { char* r = p; p += (bytes + 255) & ~255ULL; return r; };
    unsigned short* xb    = (unsigned short*)take(BSD * 2);
    unsigned short* yb    = (unsigned short*)take(BSD * 2);
    unsigned short* delta = (unsigned short*)take(BSD * 2);
    char*           uni   = take(BSF * 2);
    unsigned short* Kb    = (unsigned short*)uni;
    unsigned short* Vt    = Kb + BSD;
    unsigned short* attnb = Vt + BSD;
    unsigned short* hb    = (unsigned short*)uni;

    const size_t base4    = (size_t)(p - (char*)d_ws);
    const size_t wall_sz  = (size_t)L_ * (3 * WDD + 2 * WFD) * 2;   // 46.1 MB
    const bool   use_wall = ws_size >= base4 + wall_sz + BSD * 8 + 1024;

    unsigned short *wkb, *wvb, *wob, *w1b, *w2b, *wslot = nullptr;
    if (use_wall) {
        wkb = (unsigned short*)take(L_ * WDD * 2);
        wvb = (unsigned short*)take(L_ * WDD * 2);
        wob = (unsigned short*)take(L_ * WDD * 2);
        w1b = (unsigned short*)take(L_ * WFD * 2);
        w2b = (unsigned short*)take(L_ * WFD * 2);
    } else {
        wslot = (unsigned short*)take(WFD * 2);
        wkb = wvb = wob = w1b = w2b = nullptr;
    }

    const size_t used   = (size_t)(p - (char*)d_ws);
    const bool   use_sk = ws_size >= used + BSD * 8 + 256;
    float* pbuf = use_sk ? (float*)take(BSD * 8) : nullptr;

    init_xy<<<(int)(BSD / 4 / 256), 256, 0, stream>>>(qe, qa, pe, xb, yb);

    if (use_wall) {
        const size_t total_elems = (size_t)L_ * (3 * WDD + 2 * WFD);
        cvt_all<<<(int)(total_elems / 1024), 256, 0, stream>>>(
            Wk, Wv, Wo, W1, W2, wkb);
    }

    const int M = B_ * S_;
    for (int l = 0; l < L_; ++l) {
        const unsigned short* wk_l;
        const unsigned short* wv_l;
        const unsigned short* wo_l;
        const unsigned short* w1_l;
        const unsigned short* w2_l;
        if (use_wall) {
            wk_l = wkb + (size_t)l * WDD;
            wv_l = wvb + (size_t)l * WDD;
            wo_l = wob + (size_t)l * WDD;
            w1_l = w1b + (size_t)l * WFD;
            w2_l = w2b + (size_t)l * WFD;
        }

        if (use_wall) {
            gemm_kv<<<dim3(D_ / 128, M / 128, 2), 256, 0, stream>>>(
                xb, yb, wk_l, wv_l, bk + l * D_, bv + l * D_, Kb, Vt, M, D_, D_);
        } else {
            cvt_bf16<<<(int)(WDD / 1024), 256, 0, stream>>>(Wk + l * WDD, wslot);
            gemm_bt<false, 1><<<dim3(D_ / 128, M / 128), 256, 0, stream>>>(
                xb, wslot, bk + l * D_, Kb, M, D_, D_);
            cvt_bf16<<<(int)(WDD / 1024), 256, 0, stream>>>(Wv + l * WDD, wslot);
            gemm_bt<false, 2><<<dim3(D_ / 128, M / 128), 256, 0, stream>>>(
                yb, wslot, bv + l * D_, Vt, M, D_, D_);
        }

        attn_mfma<<<dim3(8, B_ * H_), 256, 0, stream>>>(Kb, Vt, attnb);

        if (!use_wall) { cvt_bf16<<<(int)(WDD / 1024), 256, 0, stream>>>(Wo + l * WDD, wslot); wo_l = wslot; }
        gemm_bt<false, 1><<<dim3(D_ / 128, M / 128), 256, 0, stream>>>(
            attnb, wo_l, bo + l * D_, delta, M, D_, D_);

        ln_res<false><<<M, 256, 0, stream>>>(xb, delta, ln1g + l * D_, ln1b + l * D_, xb, nullptr);

        if (!use_wall) { cvt_bf16<<<(int)(WFD / 1024), 256, 0, stream>>>(W1 + l * WFD, wslot); w1_l = wslot; }
        gemm_bt8<true><<<dim3(FF_ / 256, M / 256), 512, 0, stream>>>(
            xb, w1_l, b1 + l * FF_, hb, M, FF_, D_);

        if (!use_wall) { cvt_bf16<<<(int)(WFD / 1024), 256, 0, stream>>>(W2 + l * WFD, wslot); w2_l = wslot; }
        if (use_sk) {
            gemm_sk<<<dim3(D_ / 256, M / 256, 2), 512, 0, stream>>>(
                hb, w2_l, pbuf, M, D_, FF_, FF_ / 2);
            if (l == L_ - 1)
                ln_res_sk<true><<<M, 256, 0, stream>>>(
                    xb, pbuf, pbuf + BSD, b2 + l * D_,
                    ln2g + l * D_, ln2b + l * D_, nullptr, (float*)d_out);
            else
                ln_res_sk<false><<<M, 256, 0, stream>>>(
                    xb, pbuf, pbuf + BSD, b2 + l * D_,
                    ln2g + l * D_, ln2b + l * D_, xb, nullptr);
        } else {
            gemm_bt<false, 1><<<dim3(D_ / 128, M / 128), 256, 0, stream>>>(
                hb, w2_l, b2 + l * D_, delta, M, D_, FF_);
            if (l == L_ - 1)
                ln_res<true><<<M, 256, 0, stream>>>(xb, delta, ln2g + l * D_, ln2b + l * D_,
                                                   nullptr, (float*)d_out);
            else
                ln_res<false><<<M, 256, 0, stream>>>(xb, delta, ln2g + l * D_, ln2b + l * D_,
                                                    xb, nullptr);
        }
    }
}

// Round 13
// 776.775 us; speedup vs baseline: 1.0411x; 1.0411x over previous
//
#include <hip/hip_runtime.h>
#include <hip/hip_bf16.h>
#include <cstdint>
#include <cstddef>

#define B_  8
#define S_  1024
#define D_  1024
#define H_  8
#define FF_ 4096
#define L_  2
#define DK_ 128

typedef __bf16 bf16x8 __attribute__((ext_vector_type(8)));
typedef float  f32x4  __attribute__((ext_vector_type(4)));

__device__ __forceinline__ unsigned short f2bf(float f) {
    union { float f; uint32_t u; } v; v.f = f;
    uint32_t r = v.u + 0x7fffu + ((v.u >> 16) & 1u);
    return (unsigned short)(r >> 16);
}
__device__ __forceinline__ float bf2f(unsigned short u) {
    union { uint32_t u; float f; } v; v.u = ((uint32_t)u) << 16; return v.f;
}

// ---------------------------------------------------------------- init: xb = qe+pe, yb = qa+pe (bf16)
__global__ __launch_bounds__(256) void init_xy(
    const float* __restrict__ qe, const float* __restrict__ qa,
    const float* __restrict__ pe,
    unsigned short* __restrict__ xb, unsigned short* __restrict__ yb)
{
    int i = (blockIdx.x * 256 + threadIdx.x) * 4;
    int pi = i & (S_ * D_ - 1);
    float4 q = *(const float4*)(qe + i);
    float4 a = *(const float4*)(qa + i);
    float4 p = *(const float4*)(pe + pi);
    ushort4 xo; xo.x = f2bf(q.x + p.x); xo.y = f2bf(q.y + p.y);
    xo.z = f2bf(q.z + p.z); xo.w = f2bf(q.w + p.w);
    ushort4 yo; yo.x = f2bf(a.x + p.x); yo.y = f2bf(a.y + p.y);
    yo.z = f2bf(a.z + p.z); yo.w = f2bf(a.w + p.w);
    *(ushort4*)(xb + i) = xo;
    *(ushort4*)(yb + i) = yo;
}

// ---------------------------------------------------------------- fp32 -> bf16 weight convert (single tensor)
__global__ __launch_bounds__(256) void cvt_bf16(
    const float* __restrict__ in, unsigned short* __restrict__ out)
{
    int i = (blockIdx.x * 256 + threadIdx.x) * 4;
    float4 f = *(const float4*)(in + i);
    ushort4 o; o.x = f2bf(f.x); o.y = f2bf(f.y); o.z = f2bf(f.z); o.w = f2bf(f.w);
    *(ushort4*)(out + i) = o;
}

// ---------------------------------------------------------------- fp32 -> bf16, all 5 weight tensors, 1 launch
__global__ __launch_bounds__(256) void cvt_all(
    const float* __restrict__ wk, const float* __restrict__ wv,
    const float* __restrict__ wo, const float* __restrict__ w1,
    const float* __restrict__ w2, unsigned short* __restrict__ out)
{
    const size_t E0 = (size_t)L_ * D_ * D_;      // Wk
    const size_t E1 = 2 * E0;                    // +Wv
    const size_t E2 = 3 * E0;                    // +Wo
    const size_t E3 = E2 + (size_t)L_ * FF_ * D_;// +W1
    size_t i = ((size_t)blockIdx.x * 256 + threadIdx.x) * 4;
    const float* src;
    size_t off;
    if      (i < E0) { src = wk; off = i; }
    else if (i < E1) { src = wv; off = i - E0; }
    else if (i < E2) { src = wo; off = i - E1; }
    else if (i < E3) { src = w1; off = i - E2; }
    else             { src = w2; off = i - E3; }
    float4 f = *(const float4*)(src + off);
    ushort4 o; o.x = f2bf(f.x); o.y = f2bf(f.y); o.z = f2bf(f.z); o.w = f2bf(f.w);
    *(ushort4*)(out + i) = o;
}

// ---------------------------------------------------------------- dbuf m97-style bf16 MFMA NT-GEMM
// 128x128 tile, 4 waves. Proven ~820 TF on the N=1024 shapes.
// OMODE: 1 = bf16 row-major out; 2 = bf16 per-head-transposed [b,h][dim][key]
template<bool RELU, int OMODE>
__global__ __launch_bounds__(256) void gemm_bt(
    const unsigned short* __restrict__ A, const unsigned short* __restrict__ W,
    const float* __restrict__ bias, void* __restrict__ Cout,
    int M, int N, int K)
{
    __shared__ unsigned short sA[2][128][64];   // 2 x 16 KB
    __shared__ unsigned short sW[2][128][64];   // 2 x 16 KB

    const int tid  = threadIdx.x;
    const int lane = tid & 63;
    const int w    = tid >> 6;
    const int l16  = lane & 15;
    const int quad = lane >> 4;
    const int m0 = blockIdx.y * 128;
    const int n0 = blockIdx.x * 128;
    const int rw = (w >> 1) * 64;
    const int cw = (w & 1) * 64;

    const int srow   = lane >> 3;
    const int schunk = lane & 7;

    auto stage = [&](int k0, int buf) {
        #pragma unroll
        for (int i = 0; i < 4; ++i) {
            int r0  = w * 32 + i * 8;
            int row = r0 + srow;
            int gc  = schunk ^ (row & 7);
            const unsigned short* ga = A + (size_t)(m0 + row) * K + k0 + gc * 8;
            const unsigned short* gw = W + (size_t)(n0 + row) * K + k0 + gc * 8;
            __builtin_amdgcn_global_load_lds(
                (const __attribute__((address_space(1))) unsigned int*)ga,
                (__attribute__((address_space(3))) unsigned int*)&sA[buf][r0][0], 16, 0, 0);
            __builtin_amdgcn_global_load_lds(
                (const __attribute__((address_space(1))) unsigned int*)gw,
                (__attribute__((address_space(3))) unsigned int*)&sW[buf][r0][0], 16, 0, 0);
        }
    };

    f32x4 acc[4][4] = {};
    const int NK = K >> 6;
    int cur = 0;
    stage(0, 0);

    for (int kt = 0; kt < NK; ++kt) {
        __syncthreads();
        if (kt + 1 < NK) stage((kt + 1) << 6, cur ^ 1);

        #pragma unroll
        for (int ks = 0; ks < 2; ++ks) {
            bf16x8 af[4], wf[4];
            #pragma unroll
            for (int t = 0; t < 4; ++t) {
                int arow = rw + t * 16 + l16;
                int achk = (ks * 4 + quad) ^ (arow & 7);
                af[t] = *(const bf16x8*)&sA[cur][arow][achk * 8];
                int wrow = cw + t * 16 + l16;
                int wchk = (ks * 4 + quad) ^ (wrow & 7);
                wf[t] = *(const bf16x8*)&sW[cur][wrow][wchk * 8];
            }
            #pragma unroll
            for (int it = 0; it < 4; ++it)
                #pragma unroll
                for (int jt = 0; jt < 4; ++jt)
                    acc[it][jt] = __builtin_amdgcn_mfma_f32_16x16x32_bf16(
                        af[it], wf[jt], acc[it][jt], 0, 0, 0);
        }
        cur ^= 1;
    }

    #pragma unroll
    for (int it = 0; it < 4; ++it)
        #pragma unroll
        for (int jt = 0; jt < 4; ++jt) {
            int row = m0 + rw + it * 16 + quad * 4;
            int col = n0 + cw + jt * 16 + l16;
            float bcol = bias[col];
            float v[4];
            #pragma unroll
            for (int r = 0; r < 4; ++r) {
                v[r] = acc[it][jt][r] + bcol;
                if (RELU) v[r] = fmaxf(v[r], 0.0f);
            }
            if (OMODE == 1) {
                #pragma unroll
                for (int r = 0; r < 4; ++r)
                    ((unsigned short*)Cout)[(size_t)(row + r) * N + col] = f2bf(v[r]);
            } else {
                int key = row & (S_ - 1);
                int bb  = row >> 10;
                int hh  = col >> 7, dim = col & (DK_ - 1);
                unsigned short* dst = (unsigned short*)Cout
                    + ((size_t)(bb * H_ + hh) * DK_ + dim) * S_ + key;
                ushort4 o4; o4.x = f2bf(v[0]); o4.y = f2bf(v[1]);
                o4.z = f2bf(v[2]); o4.w = f2bf(v[3]);
                *(ushort4*)dst = o4;
            }
        }
}

// ---------------------------------------------------------------- fused K+V projection (one launch)
// blockIdx.z = 0: Kb = xb*Wk^T + bk (row-major); z = 1: Vt = yb*Wv^T + bv
// (per-head-transposed). Same proven gemm_bt loop; branch is block-uniform.
__global__ __launch_bounds__(256) void gemm_kv(
    const unsigned short* __restrict__ Ax, const unsigned short* __restrict__ Ay,
    const unsigned short* __restrict__ Wk, const unsigned short* __restrict__ Wv,
    const float* __restrict__ bk, const float* __restrict__ bv,
    unsigned short* __restrict__ Kb, unsigned short* __restrict__ Vt,
    int M, int N, int K)
{
    __shared__ unsigned short sA[2][128][64];
    __shared__ unsigned short sW[2][128][64];

    const int z = blockIdx.z;
    const unsigned short* A = z ? Ay : Ax;
    const unsigned short* W = z ? Wv : Wk;
    const float* bias = z ? bv : bk;

    const int tid  = threadIdx.x;
    const int lane = tid & 63;
    const int w    = tid >> 6;
    const int l16  = lane & 15;
    const int quad = lane >> 4;
    const int m0 = blockIdx.y * 128;
    const int n0 = blockIdx.x * 128;
    const int rw = (w >> 1) * 64;
    const int cw = (w & 1) * 64;

    const int srow   = lane >> 3;
    const int schunk = lane & 7;

    auto stage = [&](int k0, int buf) {
        #pragma unroll
        for (int i = 0; i < 4; ++i) {
            int r0  = w * 32 + i * 8;
            int row = r0 + srow;
            int gc  = schunk ^ (row & 7);
            const unsigned short* ga = A + (size_t)(m0 + row) * K + k0 + gc * 8;
            const unsigned short* gw = W + (size_t)(n0 + row) * K + k0 + gc * 8;
            __builtin_amdgcn_global_load_lds(
                (const __attribute__((address_space(1))) unsigned int*)ga,
                (__attribute__((address_space(3))) unsigned int*)&sA[buf][r0][0], 16, 0, 0);
            __builtin_amdgcn_global_load_lds(
                (const __attribute__((address_space(1))) unsigned int*)gw,
                (__attribute__((address_space(3))) unsigned int*)&sW[buf][r0][0], 16, 0, 0);
        }
    };

    f32x4 acc[4][4] = {};
    const int NK = K >> 6;
    int cur = 0;
    stage(0, 0);

    for (int kt = 0; kt < NK; ++kt) {
        __syncthreads();
        if (kt + 1 < NK) stage((kt + 1) << 6, cur ^ 1);

        #pragma unroll
        for (int ks = 0; ks < 2; ++ks) {
            bf16x8 af[4], wf[4];
            #pragma unroll
            for (int t = 0; t < 4; ++t) {
                int arow = rw + t * 16 + l16;
                int achk = (ks * 4 + quad) ^ (arow & 7);
                af[t] = *(const bf16x8*)&sA[cur][arow][achk * 8];
                int wrow = cw + t * 16 + l16;
                int wchk = (ks * 4 + quad) ^ (wrow & 7);
                wf[t] = *(const bf16x8*)&sW[cur][wrow][wchk * 8];
            }
            #pragma unroll
            for (int it = 0; it < 4; ++it)
                #pragma unroll
                for (int jt = 0; jt < 4; ++jt)
                    acc[it][jt] = __builtin_amdgcn_mfma_f32_16x16x32_bf16(
                        af[it], wf[jt], acc[it][jt], 0, 0, 0);
        }
        cur ^= 1;
    }

    #pragma unroll
    for (int it = 0; it < 4; ++it)
        #pragma unroll
        for (int jt = 0; jt < 4; ++jt) {
            int row = m0 + rw + it * 16 + quad * 4;
            int col = n0 + cw + jt * 16 + l16;
            float bcol = bias[col];
            float v[4];
            #pragma unroll
            for (int r = 0; r < 4; ++r) v[r] = acc[it][jt][r] + bcol;
            if (z == 0) {
                #pragma unroll
                for (int r = 0; r < 4; ++r)
                    Kb[(size_t)(row + r) * N + col] = f2bf(v[r]);
            } else {
                int key = row & (S_ - 1);
                int bb  = row >> 10;
                int hh  = col >> 7, dim = col & (DK_ - 1);
                unsigned short* dst = Vt
                    + ((size_t)(bb * H_ + hh) * DK_ + dim) * S_ + key;
                ushort4 o4; o4.x = f2bf(v[0]); o4.y = f2bf(v[1]);
                o4.z = f2bf(v[2]); o4.w = f2bf(v[3]);
                *(ushort4*)dst = o4;
            }
        }
}

// ---------------------------------------------------------------- 256x256 4-phase spread counted-vmcnt NT-GEMM
// SPREAD issue (max 3 loads/phase): p0:[B0,B1,B2] p1:[B3,A0,A2] p2:[A1,A3].
// Counted waits (never 0 mid-loop): mid-tile vmcnt(6), boundary vmcnt(2).
template<bool RELU>
__global__ __launch_bounds__(512, 2) void gemm_bt8(
    const unsigned short* __restrict__ A, const unsigned short* __restrict__ W,
    const float* __restrict__ bias, unsigned short* __restrict__ Cout,
    int M, int N, int K)
{
    __shared__ unsigned short sA[2][256][64];   // 2 x 32 KB
    __shared__ unsigned short sB[2][256][64];   // 2 x 32 KB

    const int tid  = threadIdx.x;
    const int lane = tid & 63;
    const int w    = tid >> 6;
    const int l16  = lane & 15;
    const int quad = lane >> 4;
    const int wr   = w >> 2;
    const int wc   = w & 3;

    const int nwg = gridDim.x * gridDim.y;
    const int bid = blockIdx.y * gridDim.x + blockIdx.x;
    const int sb  = (bid & 7) * (nwg >> 3) + (bid >> 3);
    const int m0  = (sb / gridDim.x) * 256;
    const int n0  = (sb % gridDim.x) * 256;

    const int srow8 = lane >> 3;
    const int schk  = (lane & 7) ^ srow8;

    auto stA = [&](int i, int buf, int k0) {
        int r0 = i * 64 + w * 8;
        const unsigned short* g = A + (size_t)(m0 + r0 + srow8) * K + k0 + schk * 8;
        __builtin_amdgcn_global_load_lds(
            (const __attribute__((address_space(1))) unsigned int*)g,
            (__attribute__((address_space(3))) unsigned int*)&sA[buf][r0][0], 16, 0, 0);
    };
    auto stB = [&](int i, int buf, int k0) {
        int r0 = i * 64 + w * 8;
        const unsigned short* g = W + (size_t)(n0 + r0 + srow8) * K + k0 + schk * 8;
        __builtin_amdgcn_global_load_lds(
            (const __attribute__((address_space(1))) unsigned int*)g,
            (__attribute__((address_space(3))) unsigned int*)&sB[buf][r0][0], 16, 0, 0);
    };
    auto rdA = [&](int buf, int t, int ks) {
        int row = wr * 128 + t * 16 + l16;
        int chk = (ks * 4 + quad) ^ (row & 7);
        return *(const bf16x8*)&sA[buf][row][chk * 8];
    };
    auto rdB = [&](int buf, int j, int ks) {
        int row = wc * 64 + j * 16 + l16;
        int chk = (ks * 4 + quad) ^ (row & 7);
        return *(const bf16x8*)&sB[buf][row][chk * 8];
    };

    f32x4 acc[8][4] = {};
    const int NK = K >> 6;
    int cur = 0;

    stB(0, 0, 0); stB(1, 0, 0); stB(2, 0, 0); stB(3, 0, 0);
    stA(0, 0, 0); stA(2, 0, 0); stA(1, 0, 0); stA(3, 0, 0);
    asm volatile("s_waitcnt vmcnt(2)\n\ts_barrier" ::: "memory");

    for (int kt = 0; kt < NK; ++kt) {
        const bool pref = (kt + 1 < NK);
        const int  k1   = (kt + 1) << 6;
        const int  nb   = cur ^ 1;
        bf16x8 bfr[2][4];
        bf16x8 a0, a1, a2, a3;

        // ---- phase 0
        #pragma unroll
        for (int ks = 0; ks < 2; ++ks)
            #pragma unroll
            for (int j = 0; j < 4; ++j) bfr[ks][j] = rdB(cur, j, ks);
        a0 = rdA(cur, 0, 0); a1 = rdA(cur, 0, 1);
        a2 = rdA(cur, 1, 0); a3 = rdA(cur, 1, 1);
        if (pref) { stB(0, nb, k1); stB(1, nb, k1); stB(2, nb, k1); }
        __builtin_amdgcn_s_setprio(1);
        #pragma unroll
        for (int j = 0; j < 4; ++j) {
            acc[0][j] = __builtin_amdgcn_mfma_f32_16x16x32_bf16(a0, bfr[0][j], acc[0][j], 0, 0, 0);
            acc[1][j] = __builtin_amdgcn_mfma_f32_16x16x32_bf16(a2, bfr[0][j], acc[1][j], 0, 0, 0);
        }
        #pragma unroll
        for (int j = 0; j < 4; ++j) {
            acc[0][j] = __builtin_amdgcn_mfma_f32_16x16x32_bf16(a1, bfr[1][j], acc[0][j], 0, 0, 0);
            acc[1][j] = __builtin_amdgcn_mfma_f32_16x16x32_bf16(a3, bfr[1][j], acc[1][j], 0, 0, 0);
        }
        __builtin_amdgcn_s_setprio(0);
        asm volatile("s_barrier" ::: "memory");

        // ---- phase 1
        a0 = rdA(cur, 2, 0); a1 = rdA(cur, 2, 1);
        a2 = rdA(cur, 3, 0); a3 = rdA(cur, 3, 1);
        if (pref) { stB(3, nb, k1); stA(0, nb, k1); stA(2, nb, k1); }
        __builtin_amdgcn_s_setprio(1);
        #pragma unroll
        for (int j = 0; j < 4; ++j) {
            acc[2][j] = __builtin_amdgcn_mfma_f32_16x16x32_bf16(a0, bfr[0][j], acc[2][j], 0, 0, 0);
            acc[3][j] = __builtin_amdgcn_mfma_f32_16x16x32_bf16(a2, bfr[0][j], acc[3][j], 0, 0, 0);
        }
        #pragma unroll
        for (int j = 0; j < 4; ++j) {
            acc[2][j] = __builtin_amdgcn_mfma_f32_16x16x32_bf16(a1, bfr[1][j], acc[2][j], 0, 0, 0);
            acc[3][j] = __builtin_amdgcn_mfma_f32_16x16x32_bf16(a3, bfr[1][j], acc[3][j], 0, 0, 0);
        }
        __builtin_amdgcn_s_setprio(0);
        // mid-tile: drain THIS tile's A1,A3 (oldest 2); next tile's 6 ride
        if (pref) asm volatile("s_waitcnt vmcnt(6)\n\ts_barrier" ::: "memory");
        else      asm volatile("s_waitcnt vmcnt(0)\n\ts_barrier" ::: "memory");

        // ---- phase 2
        a0 = rdA(cur, 4, 0); a1 = rdA(cur, 4, 1);
        a2 = rdA(cur, 5, 0); a3 = rdA(cur, 5, 1);
        if (pref) { stA(1, nb, k1); stA(3, nb, k1); }
        __builtin_amdgcn_s_setprio(1);
        #pragma unroll
        for (int j = 0; j < 4; ++j) {
            acc[4][j] = __builtin_amdgcn_mfma_f32_16x16x32_bf16(a0, bfr[0][j], acc[4][j], 0, 0, 0);
            acc[5][j] = __builtin_amdgcn_mfma_f32_16x16x32_bf16(a2, bfr[0][j], acc[5][j], 0, 0, 0);
        }
        #pragma unroll
        for (int j = 0; j < 4; ++j) {
            acc[4][j] = __builtin_amdgcn_mfma_f32_16x16x32_bf16(a1, bfr[1][j], acc[4][j], 0, 0, 0);
            acc[5][j] = __builtin_amdgcn_mfma_f32_16x16x32_bf16(a3, bfr[1][j], acc[5][j], 0, 0, 0);
        }
        __builtin_amdgcn_s_setprio(0);
        asm volatile("s_barrier" ::: "memory");

        // ---- phase 3
        a0 = rdA(cur, 6, 0); a1 = rdA(cur, 6, 1);
        a2 = rdA(cur, 7, 0); a3 = rdA(cur, 7, 1);
        __builtin_amdgcn_s_setprio(1);
        #pragma unroll
        for (int j = 0; j < 4; ++j) {
            acc[6][j] = __builtin_amdgcn_mfma_f32_16x16x32_bf16(a0, bfr[0][j], acc[6][j], 0, 0, 0);
            acc[7][j] = __builtin_amdgcn_mfma_f32_16x16x32_bf16(a2, bfr[0][j], acc[7][j], 0, 0, 0);
        }
        #pragma unroll
        for (int j = 0; j < 4; ++j) {
            acc[6][j] = __builtin_amdgcn_mfma_f32_16x16x32_bf16(a1, bfr[1][j], acc[6][j], 0, 0, 0);
            acc[7][j] = __builtin_amdgcn_mfma_f32_16x16x32_bf16(a3, bfr[1][j], acc[7][j], 0, 0, 0);
        }
        __builtin_amdgcn_s_setprio(0);
        asm volatile("s_waitcnt vmcnt(2)\n\ts_barrier" ::: "memory");
        cur = nb;
    }

    #pragma unroll
    for (int t = 0; t < 8; ++t)
        #pragma unroll
        for (int j = 0; j < 4; ++j) {
            int row = m0 + wr * 128 + t * 16 + quad * 4;
            int col = n0 + wc * 64 + j * 16 + l16;
            float bcol = bias[col];
            #pragma unroll
            for (int r = 0; r < 4; ++r) {
                float v = acc[t][j][r] + bcol;
                if (RELU) v = fmaxf(v, 0.0f);
                Cout[(size_t)(row + r) * N + col] = f2bf(v);
            }
        }
}

// ---------------------------------------------------------------- split-K gemm_bt8: fp32 partials, no bias
__global__ __launch_bounds__(512, 2) void gemm_sk(
    const unsigned short* __restrict__ A, const unsigned short* __restrict__ W,
    float* __restrict__ P, int M, int N, int K, int Kh)
{
    __shared__ unsigned short sA[2][256][64];
    __shared__ unsigned short sB[2][256][64];

    const int tid  = threadIdx.x;
    const int lane = tid & 63;
    const int w    = tid >> 6;
    const int l16  = lane & 15;
    const int quad = lane >> 4;
    const int wr   = w >> 2;
    const int wc   = w & 3;

    const int nwg = gridDim.x * gridDim.y;
    const int bid = blockIdx.y * gridDim.x + blockIdx.x;
    const int sb  = (bid & 7) * (nwg >> 3) + (bid >> 3);
    const int m0  = (sb / gridDim.x) * 256;
    const int n0  = (sb % gridDim.x) * 256;
    const int kb  = blockIdx.z * Kh;
    P += (size_t)blockIdx.z * M * N;

    const int srow8 = lane >> 3;
    const int schk  = (lane & 7) ^ srow8;

    auto stA = [&](int i, int buf, int k0) {
        int r0 = i * 64 + w * 8;
        const unsigned short* g = A + (size_t)(m0 + r0 + srow8) * K + k0 + schk * 8;
        __builtin_amdgcn_global_load_lds(
            (const __attribute__((address_space(1))) unsigned int*)g,
            (__attribute__((address_space(3))) unsigned int*)&sA[buf][r0][0], 16, 0, 0);
    };
    auto stB = [&](int i, int buf, int k0) {
        int r0 = i * 64 + w * 8;
        const unsigned short* g = W + (size_t)(n0 + r0 + srow8) * K + k0 + schk * 8;
        __builtin_amdgcn_global_load_lds(
            (const __attribute__((address_space(1))) unsigned int*)g,
            (__attribute__((address_space(3))) unsigned int*)&sB[buf][r0][0], 16, 0, 0);
    };
    auto rdA = [&](int buf, int t, int ks) {
        int row = wr * 128 + t * 16 + l16;
        int chk = (ks * 4 + quad) ^ (row & 7);
        return *(const bf16x8*)&sA[buf][row][chk * 8];
    };
    auto rdB = [&](int buf, int j, int ks) {
        int row = wc * 64 + j * 16 + l16;
        int chk = (ks * 4 + quad) ^ (row & 7);
        return *(const bf16x8*)&sB[buf][row][chk * 8];
    };

    f32x4 acc[8][4] = {};
    const int NK = Kh >> 6;
    int cur = 0;

    stB(0, 0, kb); stB(1, 0, kb); stB(2, 0, kb); stB(3, 0, kb);
    stA(0, 0, kb); stA(2, 0, kb); stA(1, 0, kb); stA(3, 0, kb);
    asm volatile("s_waitcnt vmcnt(2)\n\ts_barrier" ::: "memory");

    for (int kt = 0; kt < NK; ++kt) {
        const bool pref = (kt + 1 < NK);
        const int  k1   = kb + ((kt + 1) << 6);
        const int  nb   = cur ^ 1;
        bf16x8 bfr[2][4];
        bf16x8 a0, a1, a2, a3;

        // ---- phase 0
        #pragma unroll
        for (int ks = 0; ks < 2; ++ks)
            #pragma unroll
            for (int j = 0; j < 4; ++j) bfr[ks][j] = rdB(cur, j, ks);
        a0 = rdA(cur, 0, 0); a1 = rdA(cur, 0, 1);
        a2 = rdA(cur, 1, 0); a3 = rdA(cur, 1, 1);
        if (pref) { stB(0, nb, k1); stB(1, nb, k1); stB(2, nb, k1); }
        __builtin_amdgcn_s_setprio(1);
        #pragma unroll
        for (int j = 0; j < 4; ++j) {
            acc[0][j] = __builtin_amdgcn_mfma_f32_16x16x32_bf16(a0, bfr[0][j], acc[0][j], 0, 0, 0);
            acc[1][j] = __builtin_amdgcn_mfma_f32_16x16x32_bf16(a2, bfr[0][j], acc[1][j], 0, 0, 0);
        }
        #pragma unroll
        for (int j = 0; j < 4; ++j) {
            acc[0][j] = __builtin_amdgcn_mfma_f32_16x16x32_bf16(a1, bfr[1][j], acc[0][j], 0, 0, 0);
            acc[1][j] = __builtin_amdgcn_mfma_f32_16x16x32_bf16(a3, bfr[1][j], acc[1][j], 0, 0, 0);
        }
        __builtin_amdgcn_s_setprio(0);
        asm volatile("s_barrier" ::: "memory");

        // ---- phase 1
        a0 = rdA(cur, 2, 0); a1 = rdA(cur, 2, 1);
        a2 = rdA(cur, 3, 0); a3 = rdA(cur, 3, 1);
        if (pref) { stB(3, nb, k1); stA(0, nb, k1); stA(2, nb, k1); }
        __builtin_amdgcn_s_setprio(1);
        #pragma unroll
        for (int j = 0; j < 4; ++j) {
            acc[2][j] = __builtin_amdgcn_mfma_f32_16x16x32_bf16(a0, bfr[0][j], acc[2][j], 0, 0, 0);
            acc[3][j] = __builtin_amdgcn_mfma_f32_16x16x32_bf16(a2, bfr[0][j], acc[3][j], 0, 0, 0);
        }
        #pragma unroll
        for (int j = 0; j < 4; ++j) {
            acc[2][j] = __builtin_amdgcn_mfma_f32_16x16x32_bf16(a1, bfr[1][j], acc[2][j], 0, 0, 0);
            acc[3][j] = __builtin_amdgcn_mfma_f32_16x16x32_bf16(a3, bfr[1][j], acc[3][j], 0, 0, 0);
        }
        __builtin_amdgcn_s_setprio(0);
        if (pref) asm volatile("s_waitcnt vmcnt(6)\n\ts_barrier" ::: "memory");
        else      asm volatile("s_waitcnt vmcnt(0)\n\ts_barrier" ::: "memory");

        // ---- phase 2
        a0 = rdA(cur, 4, 0); a1 = rdA(cur, 4, 1);
        a2 = rdA(cur, 5, 0); a3 = rdA(cur, 5, 1);
        if (pref) { stA(1, nb, k1); stA(3, nb, k1); }
        __builtin_amdgcn_s_setprio(1);
        #pragma unroll
        for (int j = 0; j < 4; ++j) {
            acc[4][j] = __builtin_amdgcn_mfma_f32_16x16x32_bf16(a0, bfr[0][j], acc[4][j], 0, 0, 0);
            acc[5][j] = __builtin_amdgcn_mfma_f32_16x16x32_bf16(a2, bfr[0][j], acc[5][j], 0, 0, 0);
        }
        #pragma unroll
        for (int j = 0; j < 4; ++j) {
            acc[4][j] = __builtin_amdgcn_mfma_f32_16x16x32_bf16(a1, bfr[1][j], acc[4][j], 0, 0, 0);
            acc[5][j] = __builtin_amdgcn_mfma_f32_16x16x32_bf16(a3, bfr[1][j], acc[5][j], 0, 0, 0);
        }
        __builtin_amdgcn_s_setprio(0);
        asm volatile("s_barrier" ::: "memory");

        // ---- phase 3
        a0 = rdA(cur, 6, 0); a1 = rdA(cur, 6, 1);
        a2 = rdA(cur, 7, 0); a3 = rdA(cur, 7, 1);
        __builtin_amdgcn_s_setprio(1);
        #pragma unroll
        for (int j = 0; j < 4; ++j) {
            acc[6][j] = __builtin_amdgcn_mfma_f32_16x16x32_bf16(a0, bfr[0][j], acc[6][j], 0, 0, 0);
            acc[7][j] = __builtin_amdgcn_mfma_f32_16x16x32_bf16(a2, bfr[0][j], acc[7][j], 0, 0, 0);
        }
        #pragma unroll
        for (int j = 0; j < 4; ++j) {
            acc[6][j] = __builtin_amdgcn_mfma_f32_16x16x32_bf16(a1, bfr[1][j], acc[6][j], 0, 0, 0);
            acc[7][j] = __builtin_amdgcn_mfma_f32_16x16x32_bf16(a3, bfr[1][j], acc[7][j], 0, 0, 0);
        }
        __builtin_amdgcn_s_setprio(0);
        asm volatile("s_waitcnt vmcnt(2)\n\ts_barrier" ::: "memory");
        cur = nb;
    }

    #pragma unroll
    for (int t = 0; t < 8; ++t)
        #pragma unroll
        for (int j = 0; j < 4; ++j) {
            int row = m0 + wr * 128 + t * 16 + quad * 4;
            int col = n0 + wc * 64 + j * 16 + l16;
            #pragma unroll
            for (int r = 0; r < 4; ++r)
                P[(size_t)(row + r) * N + col] = acc[t][j][r];
        }
}

// ---------------------------------------------------------------- MFMA flash attention (proven form)
// Q == K (kq_same). Strict causal (j < q). Row 0 output = 0 (zero_pad).
// XCD-locality swizzle; defer-max (THR=8); K+V LDS dbuf via global_load_lds.
__global__ __launch_bounds__(256) void attn_mfma(
    const unsigned short* __restrict__ Kbuf, const unsigned short* __restrict__ Vtbuf,
    unsigned short* __restrict__ Obuf)
{
    __shared__ unsigned short sK[2][64][128];
    __shared__ unsigned short sVt[2][128][64];
    __shared__ unsigned short sP[4][16][72];

    const int tid  = threadIdx.x;
    const int lane = tid & 63;
    const int w    = tid >> 6;
    const int l16  = lane & 15;
    const int quad = lane >> 4;

    const int ib   = blockIdx.y * 8 + blockIdx.x;
    const int pa   = (ib >> 3) & 7;
    const int bh   = (ib & 7) + ((ib >> 6) << 3);
    const int b    = bh >> 3, h = bh & 7;
    const unsigned short* KB  = Kbuf  + ((size_t)b * S_) * D_ + h * DK_;
    const unsigned short* VTB = Vtbuf + (size_t)bh * DK_ * S_;

    const float scale = 0.08838834764831845f;

    auto stage = [&](int kt, int buf) {
        #pragma unroll
        for (int i = 0; i < 4; ++i) {
            int r0  = w * 16 + i * 4;
            int row = r0 + (lane >> 4);
            int c   = (lane & 15) ^ (row & 15);
            const unsigned short* g = KB + (size_t)(kt * 64 + row) * D_ + c * 8;
            __builtin_amdgcn_global_load_lds(
                (const __attribute__((address_space(1))) unsigned int*)g,
                (__attribute__((address_space(3))) unsigned int*)&sK[buf][r0][0], 16, 0, 0);
        }
        #pragma unroll
        for (int i = 0; i < 4; ++i) {
            int r0  = w * 32 + i * 8;
            int row = r0 + (lane >> 3);
            int c   = (lane & 7) ^ (row & 7);
            const unsigned short* g = VTB + (size_t)row * S_ + kt * 64 + c * 8;
            __builtin_amdgcn_global_load_lds(
                (const __attribute__((address_space(1))) unsigned int*)g,
                (__attribute__((address_space(3))) unsigned int*)&sVt[buf][r0][0], 16, 0, 0);
        }
    };

    #pragma unroll
    for (int half = 0; half < 2; ++half) {
        const int qt = half == 0 ? (15 - pa) : pa;
        const int q0 = qt * 64;

        bf16x8 qf[4];
        {
            const unsigned short* qrow = KB + (size_t)(q0 + w * 16 + l16) * D_ + quad * 8;
            #pragma unroll
            for (int ks = 0; ks < 4; ++ks)
                qf[ks] = *(const bf16x8*)(qrow + ks * 32);
        }

        f32x4 Oacc[8] = {};
        float m_run[4] = {-1e30f, -1e30f, -1e30f, -1e30f};
        float l_run[4] = {};

        int cur = 0;
        stage(0, cur);

        for (int kt = 0; kt <= qt; ++kt) {
            __syncthreads();
            if (kt < qt) stage(kt + 1, cur ^ 1);

            f32x4 sacc[4];
            __builtin_amdgcn_s_setprio(1);
            #pragma unroll
            for (int nt = 0; nt < 4; ++nt) {
                f32x4 a = {};
                #pragma unroll
                for (int ks = 0; ks < 4; ++ks) {
                    int kr = nt * 16 + l16;
                    int p  = (ks * 4 + quad) ^ (kr & 15);
                    bf16x8 kf = *(const bf16x8*)&sK[cur][kr][p * 8];
                    a = __builtin_amdgcn_mfma_f32_16x16x32_bf16(qf[ks], kf, a, 0, 0, 0);
                }
                sacc[nt] = a;
            }
            __builtin_amdgcn_s_setprio(0);

            const bool diag = (kt == qt);
            #pragma unroll
            for (int nt = 0; nt < 4; ++nt)
                #pragma unroll
                for (int r = 0; r < 4; ++r) {
                    float v = sacc[nt][r] * scale;
                    if (diag) {
                        int nidx = nt * 16 + l16;
                        int midx = w * 16 + quad * 4 + r;
                        if (nidx >= midx) v = -1e30f;
                    }
                    sacc[nt][r] = v;
                }

            float mx[4];
            #pragma unroll
            for (int r = 0; r < 4; ++r) {
                float m = fmaxf(fmaxf(sacc[0][r], sacc[1][r]), fmaxf(sacc[2][r], sacc[3][r]));
                m = fmaxf(m, __shfl_xor(m, 1));
                m = fmaxf(m, __shfl_xor(m, 2));
                m = fmaxf(m, __shfl_xor(m, 4));
                m = fmaxf(m, __shfl_xor(m, 8));
                mx[r] = m;
            }
            bool need = false;
            #pragma unroll
            for (int r = 0; r < 4; ++r) need |= (mx[r] > m_run[r] + 8.0f);
            if (__any(need)) {
                #pragma unroll
                for (int r = 0; r < 4; ++r) {
                    float mn = fmaxf(m_run[r], mx[r]);
                    float alpha = __expf(m_run[r] - mn);
                    m_run[r] = mn;
                    l_run[r] *= alpha;
                    #pragma unroll
                    for (int o = 0; o < 8; ++o) Oacc[o][r] *= alpha;
                }
            }
            #pragma unroll
            for (int r = 0; r < 4; ++r) {
                float rs = 0.0f;
                #pragma unroll
                for (int nt = 0; nt < 4; ++nt) {
                    float e = __expf(sacc[nt][r] - m_run[r]);
                    sacc[nt][r] = e;
                    rs += e;
                }
                rs += __shfl_xor(rs, 1);
                rs += __shfl_xor(rs, 2);
                rs += __shfl_xor(rs, 4);
                rs += __shfl_xor(rs, 8);
                l_run[r] += rs;
            }

            #pragma unroll
            for (int nt = 0; nt < 4; ++nt)
                #pragma unroll
                for (int r = 0; r < 4; ++r)
                    sP[w][quad * 4 + r][nt * 16 + l16] = f2bf(sacc[nt][r]);

            bf16x8 pf[2];
            #pragma unroll
            for (int ks = 0; ks < 2; ++ks)
                pf[ks] = *(const bf16x8*)&sP[w][l16][ks * 32 + quad * 8];
            __builtin_amdgcn_s_setprio(1);
            #pragma unroll
            for (int nt = 0; nt < 8; ++nt) {
                #pragma unroll
                for (int ks = 0; ks < 2; ++ks) {
                    int vr = nt * 16 + l16;
                    int p  = (ks * 4 + quad) ^ (vr & 7);
                    bf16x8 vf = *(const bf16x8*)&sVt[cur][vr][p * 8];
                    Oacc[nt] = __builtin_amdgcn_mfma_f32_16x16x32_bf16(pf[ks], vf, Oacc[nt], 0, 0, 0);
                }
            }
            __builtin_amdgcn_s_setprio(0);
            cur ^= 1;
        }

        float inv[4];
        #pragma unroll
        for (int r = 0; r < 4; ++r) {
            int m = q0 + w * 16 + quad * 4 + r;
            inv[r] = (l_run[r] > 0.0f && m != 0) ? 1.0f / l_run[r] : 0.0f;
        }
        #pragma unroll
        for (int nt = 0; nt < 8; ++nt)
            #pragma unroll
            for (int r = 0; r < 4; ++r) {
                int m = q0 + w * 16 + quad * 4 + r;
                Obuf[((size_t)b * S_ + m) * D_ + h * DK_ + nt * 16 + l16] =
                    f2bf(Oacc[nt][r] * inv[r]);
            }
    }
}

// ---------------------------------------------------------------- residual + LayerNorm (bf16 delta)
template<bool FINAL>
__global__ __launch_bounds__(256) void ln_res(
    const unsigned short* __restrict__ xin, const unsigned short* __restrict__ delta,
    const float* __restrict__ g, const float* __restrict__ bta,
    unsigned short* __restrict__ xbout, float* __restrict__ fout)
{
    __shared__ float red1[4], red2[4];
    const int row = blockIdx.x;
    const int tid = threadIdx.x;
    const int c = tid * 4;
    ushort4 xu = *(const ushort4*)(xin + (size_t)row * D_ + c);
    ushort4 du = *(const ushort4*)(delta + (size_t)row * D_ + c);
    float t0 = bf2f(xu.x) + bf2f(du.x), t1 = bf2f(xu.y) + bf2f(du.y);
    float t2 = bf2f(xu.z) + bf2f(du.z), t3 = bf2f(xu.w) + bf2f(du.w);

    float s = t0 + t1 + t2 + t3;
    #pragma unroll
    for (int off = 32; off > 0; off >>= 1) s += __shfl_down(s, off);
    if ((tid & 63) == 0) red1[tid >> 6] = s;
    __syncthreads();
    float mean = (red1[0] + red1[1] + red1[2] + red1[3]) * (1.0f / 1024.0f);

    float e0 = t0 - mean, e1 = t1 - mean, e2 = t2 - mean, e3 = t3 - mean;
    float ss = e0 * e0 + e1 * e1 + e2 * e2 + e3 * e3;
    #pragma unroll
    for (int off = 32; off > 0; off >>= 1) ss += __shfl_down(ss, off);
    if ((tid & 63) == 0) red2[tid >> 6] = ss;
    __syncthreads();
    float var = (red2[0] + red2[1] + red2[2] + red2[3]) * (1.0f / 1024.0f);
    float rstd = rsqrtf(var + 1e-5f);

    float4 gv = *(const float4*)(g + c);
    float4 bv = *(const float4*)(bta + c);
    float o0 = e0 * rstd * gv.x + bv.x;
    float o1 = e1 * rstd * gv.y + bv.y;
    float o2 = e2 * rstd * gv.z + bv.z;
    float o3 = e3 * rstd * gv.w + bv.w;
    if (FINAL) {
        *(float4*)(fout + (size_t)row * D_ + c) = make_float4(o0, o1, o2, o3);
    } else {
        ushort4 ob; ob.x = f2bf(o0); ob.y = f2bf(o1); ob.z = f2bf(o2); ob.w = f2bf(o3);
        *(ushort4*)(xbout + (size_t)row * D_ + c) = ob;
    }
}

// ---------------------------------------------------------------- residual + LN, split-K combine fused
template<bool FINAL>
__global__ __launch_bounds__(256) void ln_res_sk(
    const unsigned short* __restrict__ xin,
    const float* __restrict__ p0, const float* __restrict__ p1,
    const float* __restrict__ wbias,
    const float* __restrict__ g, const float* __restrict__ bta,
    unsigned short* __restrict__ xbout, float* __restrict__ fout)
{
    __shared__ float red1[4], red2[4];
    const int row = blockIdx.x;
    const int tid = threadIdx.x;
    const int c = tid * 4;
    ushort4 xu = *(const ushort4*)(xin + (size_t)row * D_ + c);
    float4 a0 = *(const float4*)(p0 + (size_t)row * D_ + c);
    float4 a1 = *(const float4*)(p1 + (size_t)row * D_ + c);
    float4 wb = *(const float4*)(wbias + c);
    float t0 = bf2f(xu.x) + a0.x + a1.x + wb.x;
    float t1 = bf2f(xu.y) + a0.y + a1.y + wb.y;
    float t2 = bf2f(xu.z) + a0.z + a1.z + wb.z;
    float t3 = bf2f(xu.w) + a0.w + a1.w + wb.w;

    float s = t0 + t1 + t2 + t3;
    #pragma unroll
    for (int off = 32; off > 0; off >>= 1) s += __shfl_down(s, off);
    if ((tid & 63) == 0) red1[tid >> 6] = s;
    __syncthreads();
    float mean = (red1[0] + red1[1] + red1[2] + red1[3]) * (1.0f / 1024.0f);

    float e0 = t0 - mean, e1 = t1 - mean, e2 = t2 - mean, e3 = t3 - mean;
    float ss = e0 * e0 + e1 * e1 + e2 * e2 + e3 * e3;
    #pragma unroll
    for (int off = 32; off > 0; off >>= 1) ss += __shfl_down(ss, off);
    if ((tid & 63) == 0) red2[tid >> 6] = ss;
    __syncthreads();
    float var = (red2[0] + red2[1] + red2[2] + red2[3]) * (1.0f / 1024.0f);
    float rstd = rsqrtf(var + 1e-5f);

    float4 gv = *(const float4*)(g + c);
    float4 bv = *(const float4*)(bta + c);
    float o0 = e0 * rstd * gv.x + bv.x;
    float o1 = e1 * rstd * gv.y + bv.y;
    float o2 = e2 * rstd * gv.z + bv.z;
    float o3 = e3 * rstd * gv.w + bv.w;
    if (FINAL) {
        *(float4*)(fout + (size_t)row * D_ + c) = make_float4(o0, o1, o2, o3);
    } else {
        ushort4 ob; ob.x = f2bf(o0); ob.y = f2bf(o1); ob.z = f2bf(o2); ob.w = f2bf(o3);
        *(ushort4*)(xbout + (size_t)row * D_ + c) = ob;
    }
}

// ---------------------------------------------------------------- driver
extern "C" void kernel_launch(void* const* d_in, const int* in_sizes, int n_in,
                              void* d_out, int out_size, void* d_ws, size_t ws_size,
                              hipStream_t stream)
{
    const float* qe   = (const float*)d_in[0];
    const float* qa   = (const float*)d_in[1];
    const float* pe   = (const float*)d_in[2];
    const float* Wk   = (const float*)d_in[3];
    const float* bk   = (const float*)d_in[4];
    const float* Wv   = (const float*)d_in[5];
    const float* bv   = (const float*)d_in[6];
    const float* Wo   = (const float*)d_in[7];
    const float* bo   = (const float*)d_in[8];
    const float* ln1g = (const float*)d_in[9];
    const float* ln1b = (const float*)d_in[10];
    const float* W1   = (const float*)d_in[11];
    const float* b1   = (const float*)d_in[12];
    const float* W2   = (const float*)d_in[13];
    const float* b2   = (const float*)d_in[14];
    const float* ln2g = (const float*)d_in[15];
    const float* ln2b = (const float*)d_in[16];

    const size_t BSD = (size_t)B_ * S_ * D_;
    const size_t BSF = (size_t)B_ * S_ * FF_;
    const size_t WDD = (size_t)D_ * D_;
    const size_t WFD = (size_t)FF_ * D_;

    char* p = (char*)d_ws;
    auto take = [&](size_t bytes) { char* r = p; p += (bytes + 255) & ~255ULL; return r; };
    unsigned short* xb    = (unsigned short*)take(BSD * 2);
    unsigned short* yb    = (unsigned short*)take(BSD * 2);
    unsigned short* delta = (unsigned short*)take(BSD * 2);
    char*           uni   = take(BSF * 2);
    unsigned short* Kb    = (unsigned short*)uni;
    unsigned short* Vt    = Kb + BSD;
    unsigned short* attnb = Vt + BSD;
    unsigned short* hb    = (unsigned short*)uni;

    const size_t base4    = (size_t)(p - (char*)d_ws);
    const size_t wall_sz  = (size_t)L_ * (3 * WDD + 2 * WFD) * 2;   // 46.1 MB
    const bool   use_wall = ws_size >= base4 + wall_sz + BSD * 8 + 1024;

    unsigned short *wkb, *wvb, *wob, *w1b, *w2b, *wslot = nullptr;
    if (use_wall) {
        wkb = (unsigned short*)take(L_ * WDD * 2);
        wvb = (unsigned short*)take(L_ * WDD * 2);
        wob = (unsigned short*)take(L_ * WDD * 2);
        w1b = (unsigned short*)take(L_ * WFD * 2);
        w2b = (unsigned short*)take(L_ * WFD * 2);
    } else {
        wslot = (unsigned short*)take(WFD * 2);
        wkb = wvb = wob = w1b = w2b = nullptr;
    }

    const size_t used   = (size_t)(p - (char*)d_ws);
    const bool   use_sk = ws_size >= used + BSD * 8 + 256;
    float* pbuf = use_sk ? (float*)take(BSD * 8) : nullptr;

    init_xy<<<(int)(BSD / 4 / 256), 256, 0, stream>>>(qe, qa, pe, xb, yb);

    if (use_wall) {
        const size_t total_elems = (size_t)L_ * (3 * WDD + 2 * WFD);
        cvt_all<<<(int)(total_elems / 1024), 256, 0, stream>>>(
            Wk, Wv, Wo, W1, W2, wkb);
    }

    const int M = B_ * S_;
    for (int l = 0; l < L_; ++l) {
        const unsigned short* wk_l;
        const unsigned short* wv_l;
        const unsigned short* wo_l;
        const unsigned short* w1_l;
        const unsigned short* w2_l;
        if (use_wall) {
            wk_l = wkb + (size_t)l * WDD;
            wv_l = wvb + (size_t)l * WDD;
            wo_l = wob + (size_t)l * WDD;
            w1_l = w1b + (size_t)l * WFD;
            w2_l = w2b + (size_t)l * WFD;
        }

        if (use_wall) {
            gemm_kv<<<dim3(D_ / 128, M / 128, 2), 256, 0, stream>>>(
                xb, yb, wk_l, wv_l, bk + l * D_, bv + l * D_, Kb, Vt, M, D_, D_);
        } else {
            cvt_bf16<<<(int)(WDD / 1024), 256, 0, stream>>>(Wk + l * WDD, wslot);
            gemm_bt<false, 1><<<dim3(D_ / 128, M / 128), 256, 0, stream>>>(
                xb, wslot, bk + l * D_, Kb, M, D_, D_);
            cvt_bf16<<<(int)(WDD / 1024), 256, 0, stream>>>(Wv + l * WDD, wslot);
            gemm_bt<false, 2><<<dim3(D_ / 128, M / 128), 256, 0, stream>>>(
                yb, wslot, bv + l * D_, Vt, M, D_, D_);
        }

        attn_mfma<<<dim3(8, B_ * H_), 256, 0, stream>>>(Kb, Vt, attnb);

        if (!use_wall) { cvt_bf16<<<(int)(WDD / 1024), 256, 0, stream>>>(Wo + l * WDD, wslot); wo_l = wslot; }
        gemm_bt<false, 1><<<dim3(D_ / 128, M / 128), 256, 0, stream>>>(
            attnb, wo_l, bo + l * D_, delta, M, D_, D_);

        ln_res<false><<<M, 256, 0, stream>>>(xb, delta, ln1g + l * D_, ln1b + l * D_, xb, nullptr);

        if (!use_wall) { cvt_bf16<<<(int)(WFD / 1024), 256, 0, stream>>>(W1 + l * WFD, wslot); w1_l = wslot; }
        gemm_bt8<true><<<dim3(FF_ / 256, M / 256), 512, 0, stream>>>(
            xb, w1_l, b1 + l * FF_, hb, M, FF_, D_);

        if (!use_wall) { cvt_bf16<<<(int)(WFD / 1024), 256, 0, stream>>>(W2 + l * WFD, wslot); w2_l = wslot; }
        if (use_sk) {
            gemm_sk<<<dim3(D_ / 256, M / 256, 2), 512, 0, stream>>>(
                hb, w2_l, pbuf, M, D_, FF_, FF_ / 2);
            if (l == L_ - 1)
                ln_res_sk<true><<<M, 256, 0, stream>>>(
                    xb, pbuf, pbuf + BSD, b2 + l * D_,
                    ln2g + l * D_, ln2b + l * D_, nullptr, (float*)d_out);
            else
                ln_res_sk<false><<<M, 256, 0, stream>>>(
                    xb, pbuf, pbuf + BSD, b2 + l * D_,
                    ln2g + l * D_, ln2b + l * D_, xb, nullptr);
        } else {
            gemm_bt<false, 1><<<dim3(D_ / 128, M / 128), 256, 0, stream>>>(
                hb, w2_l, b2 + l * D_, delta, M, D_, FF_);
            if (l == L_ - 1)
                ln_res<true><<<M, 256, 0, stream>>>(xb, delta, ln2g + l * D_, ln2b + l * D_,
                                                   nullptr, (float*)d_out);
            else
                ln_res<false><<<M, 256, 0, stream>>>(xb, delta, ln2g + l * D_, ln2b + l * D_,
                                                    xb, nullptr);
        }
    }
}